// Round 9
// baseline (2735.138 us; speedup 1.0000x reference)
//
#include <hip/hip_runtime.h>
#include <hip/hip_bf16.h>
#include <hip/hip_cooperative_groups.h>

#define NL 6
#define DM 768
#define DI 1536
#define DS 16
#define NRANK 48
#define DBC 80
#define BATCH 2
#define SEQ 1024
#define NTOK (BATCH*SEQ)
#define NCHUNK 64
#define CHLEN 16
#define XKS 8
#define XKC (DI/XKS)

typedef __attribute__((ext_vector_type(8))) short short8;
typedef __attribute__((ext_vector_type(4))) float f32x4;
typedef __attribute__((ext_vector_type(4))) unsigned short ushort4v;

__device__ inline unsigned short f2bf(float f) {
  union { float f; unsigned u; } x; x.f = f;
  unsigned r = x.u + 0x7FFF + ((x.u >> 16) & 1);
  return (unsigned short)(r >> 16);
}
__device__ inline float bf2f(unsigned short s) {
  union { unsigned u; float f; } x; x.u = ((unsigned)s) << 16;
  return x.f;
}

__device__ inline void gl_lds16(const unsigned short* g, unsigned short* l) {
  __builtin_amdgcn_global_load_lds(
      (const __attribute__((address_space(1))) unsigned int*)(g),
      (__attribute__((address_space(3))) unsigned int*)(l),
      16, 0, 0);
}

// spans (in f32x4 chunks)
#define SPAN_X   (NTOK * DM / 4)
#define SPAN_INW (NL * 2 * DI * DM / 4)
#define SPAN_OUW (NL * DM * DI / 4)
#define SPAN_XPW (NL * DBC * DI / 4)
#define SPAN_ALL (SPAN_X + SPAN_INW + SPAN_OUW + SPAN_XPW)

__device__ inline void cvt4_store(const float* s, unsigned short* d, int i) {
  f32x4 v = ((const f32x4*)s)[i];
  union { ushort4v u4; __hip_bfloat162 h[2]; } u;
  float2 p;
  p.x = v[0]; p.y = v[1]; u.h[0] = __float22bfloat162_rn(p);
  p.x = v[2]; p.y = v[3]; u.h[1] = __float22bfloat162_rn(p);
  ((ushort4v*)d)[i] = u.u4;
}

// one kernel: convert x, in_w, out_w, xp_w to bf16
__global__ __launch_bounds__(256) void cvtall_k(const float* __restrict__ x,
                                                const float* __restrict__ inw,
                                                const float* __restrict__ ouw,
                                                const float* __restrict__ xpw,
                                                unsigned short* __restrict__ xb,
                                                unsigned short* __restrict__ inwb,
                                                unsigned short* __restrict__ ouwb,
                                                unsigned short* __restrict__ xpwb) {
  for (int i = blockIdx.x * 256 + threadIdx.x; i < SPAN_ALL; i += gridDim.x * 256) {
    if (i < SPAN_X) cvt4_store(x, xb, i);
    else if (i < SPAN_X + SPAN_INW) cvt4_store(inw, inwb, i - SPAN_X);
    else if (i < SPAN_X + SPAN_INW + SPAN_OUW) cvt4_store(ouw, ouwb, i - SPAN_X - SPAN_INW);
    else cvt4_store(xpw, xpwb, i - SPAN_X - SPAN_INW - SPAN_OUW);
  }
}

// misc: dtp_w pad->bf16 [NL][1536][64] + negA = -exp(A_log)
__global__ __launch_bounds__(256) void misc_pre_k(const float* __restrict__ w,
                                                  const float* __restrict__ al,
                                                  unsigned short* __restrict__ wb,
                                                  float* __restrict__ na) {
  int idx = blockIdx.x * 256 + threadIdx.x;
  const int NDT = NL * 1536 * 64;
  if (idx < NDT) {
    int col = idx & 63;
    int row = idx >> 6;
    wb[idx] = (col < NRANK) ? f2bf(w[(size_t)row * NRANK + col]) : (unsigned short)0;
  } else if (idx < NDT + NL * DI * DS) {
    int k = idx - NDT;
    na[k] = -__expf(al[k]);
  }
}

// ---------------------------------------------------------------------------
// 128x128-tile bf16 GEMM -> bf16 output (in_proj). gl_lds + double buffer.
// ---------------------------------------------------------------------------
__global__ __launch_bounds__(256) void bt128b_k(
    const unsigned short* __restrict__ A, int lda,
    const unsigned short* __restrict__ W, int ldw,
    unsigned short* __restrict__ C, int ldc,
    int K) {
  __shared__ __align__(16) unsigned short As[2][128 * 32];
  __shared__ __align__(16) unsigned short Ws[2][128 * 32];
  const int tid = threadIdx.x;
  const int bm = blockIdx.y * 128;
  const int bn = blockIdx.x * 128;
  const int lane = tid & 63;
  const int wv = tid >> 6;
  const int wm = (wv >> 1) * 64;
  const int wn = (wv & 1) * 64;
  const int fr = lane & 15;
  const int fs = lane >> 4;

  const int r0 = tid >> 2;
  const int s0 = (tid & 3) ^ (r0 & 3);

  const unsigned short* gA0 = A + (size_t)(bm + r0) * lda + s0 * 8;
  const unsigned short* gA1 = A + (size_t)(bm + r0 + 64) * lda + s0 * 8;
  const unsigned short* gW0 = W + (size_t)(bn + r0) * ldw + s0 * 8;
  const unsigned short* gW1 = W + (size_t)(bn + r0 + 64) * ldw + s0 * 8;

  f32x4 acc[4][4];
#pragma unroll
  for (int i = 0; i < 4; i++)
#pragma unroll
    for (int j = 0; j < 4; j++) acc[i][j] = (f32x4){0.f, 0.f, 0.f, 0.f};

  gl_lds16(gA0, &As[0][0] + tid * 8);
  gl_lds16(gA1, &As[0][2048] + tid * 8);
  gl_lds16(gW0, &Ws[0][0] + tid * 8);
  gl_lds16(gW1, &Ws[0][2048] + tid * 8);
  __syncthreads();

  const int nk = K >> 5;
  int buf = 0;
  for (int kk = 0; kk < nk; kk++) {
    if (kk + 1 < nk) {
      const int k0 = (kk + 1) * 32;
      gl_lds16(gA0 + k0, &As[buf ^ 1][0] + tid * 8);
      gl_lds16(gA1 + k0, &As[buf ^ 1][2048] + tid * 8);
      gl_lds16(gW0 + k0, &Ws[buf ^ 1][0] + tid * 8);
      gl_lds16(gW1 + k0, &Ws[buf ^ 1][2048] + tid * 8);
    }

    short8 af[4], bf[4];
#pragma unroll
    for (int i = 0; i < 4; i++) {
      int rowa = wm + i * 16 + fr;
      af[i] = *(const short8*)&As[buf][rowa * 32 + ((fs ^ (rowa & 3)) * 8)];
      int rowb = wn + i * 16 + fr;
      bf[i] = *(const short8*)&Ws[buf][rowb * 32 + ((fs ^ (rowb & 3)) * 8)];
    }
#pragma unroll
    for (int i = 0; i < 4; i++)
#pragma unroll
      for (int j = 0; j < 4; j++)
        acc[i][j] = __builtin_amdgcn_mfma_f32_16x16x32_bf16(af[i], bf[j], acc[i][j], 0, 0, 0);

    __syncthreads();
    buf ^= 1;
  }

#pragma unroll
  for (int i = 0; i < 4; i++) {
#pragma unroll
    for (int j = 0; j < 4; j++) {
#pragma unroll
      for (int r = 0; r < 4; r++) {
        int row = bm + wm + i * 16 + fs * 4 + r;
        int col = bn + wn + j * 16 + fr;
        C[(size_t)row * ldc + col] = f2bf(acc[i][j][r]);
      }
    }
  }
}

// ---------------------------------------------------------------------------
// 64x64-tile bf16 GEMM. EPI 1: softplus(v+bias)->bf16. EPI 2: fp32 v+resid.
// ---------------------------------------------------------------------------
template<int EPI>
__global__ __launch_bounds__(256) void bt64_k(
    const unsigned short* __restrict__ A, int lda,
    const unsigned short* __restrict__ W, int ldw,
    void* __restrict__ Cv, int ldc,
    int K,
    const float* __restrict__ bias,
    const float* __restrict__ resid) {
  __shared__ __align__(16) unsigned short As[2][64 * 32];
  __shared__ __align__(16) unsigned short Ws[2][64 * 32];
  const int tid = threadIdx.x;
  const int bm = blockIdx.y * 64;
  const int bn = blockIdx.x * 64;
  const int lane = tid & 63;
  const int wv = tid >> 6;
  const int wm = (wv >> 1) * 32;
  const int wn = (wv & 1) * 32;
  const int fr = lane & 15;
  const int fs = lane >> 4;

  const int r0 = tid >> 2;
  const int s0 = (tid & 3) ^ (r0 & 3);

  const unsigned short* gA = A + (size_t)(bm + r0) * lda + s0 * 8;
  const unsigned short* gW = W + (size_t)(bn + r0) * ldw + s0 * 8;

  f32x4 acc[2][2];
#pragma unroll
  for (int i = 0; i < 2; i++)
#pragma unroll
    for (int j = 0; j < 2; j++) acc[i][j] = (f32x4){0.f, 0.f, 0.f, 0.f};

  gl_lds16(gA, &As[0][0] + tid * 8);
  gl_lds16(gW, &Ws[0][0] + tid * 8);
  __syncthreads();

  const int nk = K >> 5;
  int buf = 0;
  for (int kk = 0; kk < nk; kk++) {
    if (kk + 1 < nk) {
      const int k0 = (kk + 1) * 32;
      gl_lds16(gA + k0, &As[buf ^ 1][0] + tid * 8);
      gl_lds16(gW + k0, &Ws[buf ^ 1][0] + tid * 8);
    }

    short8 af[2], bf[2];
#pragma unroll
    for (int i = 0; i < 2; i++) {
      int rowa = wm + i * 16 + fr;
      af[i] = *(const short8*)&As[buf][rowa * 32 + ((fs ^ (rowa & 3)) * 8)];
      int rowb = wn + i * 16 + fr;
      bf[i] = *(const short8*)&Ws[buf][rowb * 32 + ((fs ^ (rowb & 3)) * 8)];
    }
#pragma unroll
    for (int i = 0; i < 2; i++)
#pragma unroll
      for (int j = 0; j < 2; j++)
        acc[i][j] = __builtin_amdgcn_mfma_f32_16x16x32_bf16(af[i], bf[j], acc[i][j], 0, 0, 0);

    __syncthreads();
    buf ^= 1;
  }

#pragma unroll
  for (int i = 0; i < 2; i++) {
#pragma unroll
    for (int j = 0; j < 2; j++) {
#pragma unroll
      for (int r = 0; r < 4; r++) {
        int row = bm + wm + i * 16 + fs * 4 + r;
        int col = bn + wn + j * 16 + fr;
        float v = acc[i][j][r];
        if (EPI == 1) {
          float xv = v + bias[col];
          float sp = (xv > 20.f) ? xv : log1pf(__expf(xv));
          ((unsigned short*)Cv)[(size_t)row * ldc + col] = f2bf(sp);
        }
        if (EPI == 2) {
          ((float*)Cv)[(size_t)row * ldc + col] = v + resid[(size_t)row * ldc + col];
        }
      }
    }
  }
}

// ---------------------------------------------------------------------------
// x_proj split-K, bf16
// ---------------------------------------------------------------------------
__global__ __launch_bounds__(256) void xp_k(
    const unsigned short* __restrict__ A,
    const unsigned short* __restrict__ W,
    float* __restrict__ part) {
  __shared__ __align__(16) unsigned short As[64][40];
  __shared__ __align__(16) unsigned short Ws[80][40];
  const int tid = threadIdx.x;
  const int ks = blockIdx.x;
  const int bm = blockIdx.y * 64;
  const int lane = tid & 63;
  const int wv = tid >> 6;
  const int fr = lane & 15;
  const int fs = lane >> 4;
  const int fk = fs * 8;

  const int ar = tid >> 2;
  const int ac = (tid & 3) * 8;
  const int k0base = ks * XKC;

  const unsigned short* gA  = A + (size_t)(bm + ar) * DI + k0base + ac;
  const unsigned short* gW0 = W + (size_t)ar * DI + k0base + ac;
  const unsigned short* gW1 = W + (size_t)(64 + ar) * DI + k0base + ac;

  f32x4 acc[5];
#pragma unroll
  for (int n = 0; n < 5; n++) acc[n] = (f32x4){0.f, 0.f, 0.f, 0.f};

  short8 aA, w0A, w1A;
  aA = *(const short8*)(gA);
  w0A = *(const short8*)(gW0);
  if (tid < 64) w1A = *(const short8*)(gW1);

  const int nk = XKC / 32;
  for (int kk = 0; kk < nk; kk++) {
    __syncthreads();
    *(short8*)&As[ar][ac] = aA;
    *(short8*)&Ws[ar][ac] = w0A;
    if (tid < 64) *(short8*)&Ws[64 + ar][ac] = w1A;
    __syncthreads();

    if (kk + 1 < nk) {
      const int k0 = (kk + 1) * 32;
      aA = *(const short8*)(gA + k0);
      w0A = *(const short8*)(gW0 + k0);
      if (tid < 64) w1A = *(const short8*)(gW1 + k0);
    }

    short8 af = *(const short8*)&As[wv * 16 + fr][fk];
#pragma unroll
    for (int n = 0; n < 5; n++) {
      short8 bf = *(const short8*)&Ws[n * 16 + fr][fk];
      acc[n] = __builtin_amdgcn_mfma_f32_16x16x32_bf16(af, bf, acc[n], 0, 0, 0);
    }
  }

#pragma unroll
  for (int n = 0; n < 5; n++) {
#pragma unroll
    for (int r = 0; r < 4; r++) {
      int row = bm + wv * 16 + fs * 4 + r;
      part[((size_t)ks * NTOK + row) * DBC + n * 16 + fr] = acc[n][r];
    }
  }
}

// sum XKS partials -> dbc (fp32) + bf16 zero-padded dt-input [m][64]
__global__ __launch_bounds__(256) void xp_reduce_k(const float* __restrict__ part,
                                                   float* __restrict__ dbc,
                                                   unsigned short* __restrict__ dtA) {
  int i = blockIdx.x * 256 + threadIdx.x;
  const f32x4* p4 = (const f32x4*)part;
  const int stride4 = NTOK * DBC / 4;
  f32x4 s = p4[i];
#pragma unroll
  for (int ks = 1; ks < XKS; ks++) {
    f32x4 v = p4[(size_t)ks * stride4 + i];
    s[0] += v[0]; s[1] += v[1]; s[2] += v[2]; s[3] += v[3];
  }
  ((f32x4*)dbc)[i] = s;
  int c4 = (i * 4) % DBC;
  int m = (i * 4) / DBC;
  if (c4 < 64) {
    union { ushort4v u4; __hip_bfloat162 h[2]; } u;
    if (c4 < NRANK) {
      float2 p;
      p.x = s[0]; p.y = s[1]; u.h[0] = __float22bfloat162_rn(p);
      p.x = s[2]; p.y = s[3]; u.h[1] = __float22bfloat162_rn(p);
    } else {
      u.u4 = (ushort4v){0, 0, 0, 0};
    }
    *(ushort4v*)&dtA[(size_t)m * 64 + c4] = u.u4;
  }
}

// depthwise causal conv(4) + bias + silu, register-carry; bf16 in/out
__global__ __launch_bounds__(256) void conv_silu_k(const unsigned short* __restrict__ xz,
                                                   const float* __restrict__ cw,
                                                   const float* __restrict__ cb,
                                                   unsigned short* __restrict__ xcb) {
  const int d = blockIdx.x * 256 + threadIdx.x;
  const int l0 = blockIdx.y * 16;
  const int b = blockIdx.z;
  const size_t mbase = (size_t)b * SEQ;
  const float w0 = cw[d * 4 + 0], w1 = cw[d * 4 + 1];
  const float w2 = cw[d * 4 + 2], w3 = cw[d * 4 + 3];
  const float bias = cb[d];
  float c3 = (l0 >= 3) ? bf2f(xz[(mbase + l0 - 3) * (2 * DI) + d]) : 0.f;
  float c2 = (l0 >= 2) ? bf2f(xz[(mbase + l0 - 2) * (2 * DI) + d]) : 0.f;
  float c1 = (l0 >= 1) ? bf2f(xz[(mbase + l0 - 1) * (2 * DI) + d]) : 0.f;
#pragma unroll
  for (int t = 0; t < 16; t++) {
    const int l = l0 + t;
    float cur = bf2f(xz[(mbase + l) * (2 * DI) + d]);
    float s = bias + w0 * c3 + w1 * c2 + w2 * c1 + w3 * cur;
    float sig = 1.f / (1.f + __expf(-s));
    xcb[(mbase + l) * DI + d] = f2bf(s * sig);
    c3 = c2; c2 = c1; c1 = cur;
  }
}

// ---------------------------------------------------------------------------
// FUSED scan (cooperative, __launch_bounds__(256,3) so 768 blocks co-reside):
// phase1 local scan (regs) -> fence+grid.sync -> phase2 combine (192 blocks)
// -> fence+grid.sync -> phase3 fixup + gate.
// ---------------------------------------------------------------------------
__global__ __launch_bounds__(256, 3) void scanfused_k(
    const unsigned short* __restrict__ dt,
    const unsigned short* __restrict__ xc,
    const float* __restrict__ dbc,
    const unsigned short* __restrict__ xz,
    const float* __restrict__ negA_l,
    const float* __restrict__ Dsk,
    float* __restrict__ cumA,
    float* __restrict__ hloc,
    float* __restrict__ hin,
    float* __restrict__ states_out,
    unsigned short* __restrict__ y) {
  __shared__ float Bs[CHLEN][DS];
  __shared__ float Cs[CHLEN][DS];
  const int tid = threadIdx.x;
  const int j = blockIdx.x;        // chunk
  const int cgi = blockIdx.y;      // 0..11
  const int b = cgi / 6;
  const int d = (cgi % 6) * 256 + tid;
  const int c = b * DI + d;
  const int m0 = b * SEQ + j * CHLEN;

  // ---- phase 1: local scan ----
  for (int e = tid; e < CHLEN * 32; e += 256) {
    int row = e >> 5, col = e & 31;
    float v = dbc[(size_t)(m0 + row) * DBC + NRANK + col];
    if (col < DS) Bs[row][col] = v; else Cs[row][col - DS] = v;
  }

  float Av[DS];
  const float* na = negA_l + (size_t)d * DS;
#pragma unroll
  for (int s = 0; s < DS; s++) Av[s] = na[s];
  const float Av0 = Av[0];
  bool fast = true;
#pragma unroll
  for (int s = 0; s < DS; s++)
    fast = fast && (fabsf(Av[s] - (s + 1) * Av0) <= 1e-4f * (s + 1));

  float dts[CHLEN], xcs[CHLEN];
#pragma unroll
  for (int t = 0; t < CHLEN; t++) {
    dts[t] = bf2f(dt[(size_t)(m0 + t) * DI + d]);
    xcs[t] = bf2f(xc[(size_t)(m0 + t) * DI + d]);
  }
  __syncthreads();

  float h[DS];
#pragma unroll
  for (int s = 0; s < DS; s++) h[s] = 0.f;
  float ylocr[CHLEN], cumdtr[CHLEN];
  float cd = 0.f;

#pragma unroll
  for (int t = 0; t < CHLEN; t++) {
    float dtv = dts[t];
    cd += dtv;
    float dtx = dtv * xcs[t];
    float ysum = 0.f;
    if (fast) {
      float e1 = __expf(dtv * Av0);
      float dA = e1;
      h[0] = fmaf(dA, h[0], dtx * Bs[t][0]);
      ysum = fmaf(h[0], Cs[t][0], ysum);
#pragma unroll
      for (int s = 1; s < DS; s++) {
        dA *= e1;
        h[s] = fmaf(dA, h[s], dtx * Bs[t][s]);
        ysum = fmaf(h[s], Cs[t][s], ysum);
      }
    } else {
#pragma unroll
      for (int s = 0; s < DS; s++) {
        float dA = __expf(dtv * Av[s]);
        h[s] = fmaf(dA, h[s], dtx * Bs[t][s]);
        ysum = fmaf(h[s], Cs[t][s], ysum);
      }
    }
    ylocr[t] = ysum;
    cumdtr[t] = cd;
  }

  size_t base = ((size_t)j * (BATCH * DI) + c) * DS;
#pragma unroll
  for (int s = 0; s < DS; s++) {
    cumA[base + s] = __expf(cd * Av[s]);
    hloc[base + s] = h[s];
  }

  __threadfence();
  cooperative_groups::this_grid().sync();

  // ---- phase 2: chunk combine (192 blocks) ----
  int lb = blockIdx.y * gridDim.x + blockIdx.x;  // 0..767
  if (lb < 192) {
    int idx = lb * 256 + tid;
    const int stride = BATCH * DI * DS;
    float hh = 0.f;
    for (int jj = 0; jj < NCHUNK; jj++) {
      hin[(size_t)jj * stride + idx] = hh;
      hh = fmaf(cumA[(size_t)jj * stride + idx], hh, hloc[(size_t)jj * stride + idx]);
    }
    states_out[idx] = hh;
  }

  __threadfence();
  cooperative_groups::this_grid().sync();

  // ---- phase 3: fixup + gate ----
  const f32x4* h4 = (const f32x4*)(hin + base);
  f32x4 hv[4];
#pragma unroll
  for (int q = 0; q < 4; q++) hv[q] = h4[q];
  float dval = Dsk[d];

#pragma unroll
  for (int t = 0; t < CHLEN; t++) {
    float cdv = cumdtr[t];
    float corr = 0.f;
    if (fast) {
      float e1 = __expf(cdv * Av0);
      float P = e1;
#pragma unroll
      for (int q = 0; q < 4; q++) {
#pragma unroll
        for (int e = 0; e < 4; e++) {
          int s = q * 4 + e;
          if (s > 0) P *= e1;
          corr = fmaf(P * hv[q][e], Cs[t][s], corr);
        }
      }
    } else {
#pragma unroll
      for (int q = 0; q < 4; q++) {
#pragma unroll
        for (int e = 0; e < 4; e++) {
          int s = q * 4 + e;
          corr = fmaf(__expf(cdv * Av[s]) * hv[q][e], Cs[t][s], corr);
        }
      }
    }
    float yv = ylocr[t] + corr;
    float zv = bf2f(xz[(size_t)(m0 + t) * (2 * DI) + DI + d]);
    float sig = 1.f / (1.f + __expf(-zv));
    y[(size_t)(m0 + t) * DI + d] = f2bf((yv + dval * xcs[t]) * (zv * sig));
  }
}

// ---------------- fallback scan trio (known-good R7 path) ----------------
__global__ __launch_bounds__(256) void scan1_k(const unsigned short* __restrict__ dt,
                                               const unsigned short* __restrict__ xc,
                                               const float* __restrict__ dbc,
                                               const float* __restrict__ negA_l,
                                               float* __restrict__ cumA,
                                               float* __restrict__ hloc,
                                               unsigned short* __restrict__ yloc,
                                               float* __restrict__ cumdt) {
  __shared__ float Bs[CHLEN][DS];
  __shared__ float Cs[CHLEN][DS];
  const int tid = threadIdx.x;
  const int j = blockIdx.x;
  const int cg = blockIdx.y;
  const int b = cg / 6;
  const int d = (cg % 6) * 256 + tid;
  const int c = b * DI + d;
  const int m0 = b * SEQ + j * CHLEN;

  for (int e = tid; e < CHLEN * 32; e += 256) {
    int row = e >> 5, col = e & 31;
    float v = dbc[(size_t)(m0 + row) * DBC + NRANK + col];
    if (col < DS) Bs[row][col] = v; else Cs[row][col - DS] = v;
  }

  float Av[DS];
  const float* na = negA_l + (size_t)d * DS;
#pragma unroll
  for (int s = 0; s < DS; s++) Av[s] = na[s];
  const float Av0 = Av[0];
  bool fast = true;
#pragma unroll
  for (int s = 0; s < DS; s++)
    fast = fast && (fabsf(Av[s] - (s + 1) * Av0) <= 1e-4f * (s + 1));

  float dts[CHLEN], xcs[CHLEN];
#pragma unroll
  for (int t = 0; t < CHLEN; t++) {
    dts[t] = bf2f(dt[(size_t)(m0 + t) * DI + d]);
    xcs[t] = bf2f(xc[(size_t)(m0 + t) * DI + d]);
  }
  __syncthreads();

  float h[DS];
#pragma unroll
  for (int s = 0; s < DS; s++) h[s] = 0.f;
  float cd = 0.f;

  for (int t = 0; t < CHLEN; t++) {
    float dtv = dts[t];
    cd += dtv;
    float dtx = dtv * xcs[t];
    float ysum = 0.f;
    if (fast) {
      float e1 = __expf(dtv * Av0);
      float dA = e1;
      h[0] = fmaf(dA, h[0], dtx * Bs[t][0]);
      ysum = fmaf(h[0], Cs[t][0], ysum);
#pragma unroll
      for (int s = 1; s < DS; s++) {
        dA *= e1;
        h[s] = fmaf(dA, h[s], dtx * Bs[t][s]);
        ysum = fmaf(h[s], Cs[t][s], ysum);
      }
    } else {
#pragma unroll
      for (int s = 0; s < DS; s++) {
        float dA = __expf(dtv * Av[s]);
        h[s] = fmaf(dA, h[s], dtx * Bs[t][s]);
        ysum = fmaf(h[s], Cs[t][s], ysum);
      }
    }
    size_t mi = (size_t)(m0 + t) * DI + d;
    yloc[mi] = f2bf(ysum);
    cumdt[mi] = cd;
  }

  size_t base = ((size_t)j * (BATCH * DI) + c) * DS;
#pragma unroll
  for (int s = 0; s < DS; s++) {
    cumA[base + s] = __expf(cd * Av[s]);
    hloc[base + s] = h[s];
  }
}

__global__ __launch_bounds__(256) void scan2_k(const float* __restrict__ cumA,
                                               const float* __restrict__ hloc,
                                               float* __restrict__ hin,
                                               float* __restrict__ states_out) {
  int idx = blockIdx.x * 256 + threadIdx.x;
  const int stride = BATCH * DI * DS;
  float h = 0.f;
  for (int j = 0; j < NCHUNK; j++) {
    hin[(size_t)j * stride + idx] = h;
    h = fmaf(cumA[(size_t)j * stride + idx], h, hloc[(size_t)j * stride + idx]);
  }
  states_out[idx] = h;
}

__global__ __launch_bounds__(256) void scanfix_k(const unsigned short* __restrict__ yloc,
                                                 const float* __restrict__ cumdt,
                                                 const unsigned short* __restrict__ xc,
                                                 const unsigned short* __restrict__ xz,
                                                 const float* __restrict__ dbc,
                                                 const float* __restrict__ negA_l,
                                                 const float* __restrict__ Dsk,
                                                 const float* __restrict__ hin,
                                                 unsigned short* __restrict__ y) {
  int idx = blockIdx.x * 256 + threadIdx.x;
  int d = idx % DI;
  int m = idx / DI;
  int b = m / SEQ;
  int j = (m % SEQ) / CHLEN;
  float cd = cumdt[idx];
  float yv = bf2f(yloc[idx]);
  const f32x4* na4 = (const f32x4*)(negA_l + (size_t)d * DS);
  const f32x4* cp4 = (const f32x4*)(dbc + (size_t)m * DBC + NRANK + DS);
  const f32x4* h4  = (const f32x4*)(hin + ((size_t)j * (BATCH * DI) + (size_t)b * DI + d) * DS);
  float corr = 0.f;
#pragma unroll
  for (int q = 0; q < 4; q++) {
    f32x4 na = na4[q], cp = cp4[q], hh = h4[q];
#pragma unroll
    for (int e = 0; e < 4; e++)
      corr = fmaf(__expf(cd * na[e]) * hh[e], cp[e], corr);
  }
  yv += corr;
  float xv = bf2f(xc[idx]);
  float zv = bf2f(xz[(size_t)m * (2 * DI) + DI + d]);
  float sig = 1.f / (1.f + __expf(-zv));
  y[idx] = f2bf((yv + Dsk[d] * xv) * (zv * sig));
}

// LN (w,b) then optionally LN_noaffine + adaln modulate
template<bool ADA>
__global__ __launch_bounds__(256) void ln_k(const float* __restrict__ in,
                                            const float* __restrict__ w,
                                            const float* __restrict__ bb,
                                            const float* __restrict__ ss,
                                            float* __restrict__ out,
                                            unsigned short* __restrict__ outb) {
  __shared__ float red[8];
  const int row = blockIdx.x;
  const int bt = row / SEQ;
  const int tid = threadIdx.x;
  const float* x = in + (size_t)row * DM;
  float v[3];
#pragma unroll
  for (int i = 0; i < 3; i++) v[i] = x[tid + i * 256];
  float s1 = v[0] + v[1] + v[2];
  float s2 = v[0]*v[0] + v[1]*v[1] + v[2]*v[2];
#pragma unroll
  for (int o = 32; o > 0; o >>= 1) { s1 += __shfl_down(s1, o); s2 += __shfl_down(s2, o); }
  int wv = tid >> 6, ln = tid & 63;
  if (ln == 0) { red[wv*2] = s1; red[wv*2+1] = s2; }
  __syncthreads();
  s1 = red[0] + red[2] + red[4] + red[6];
  s2 = red[1] + red[3] + red[5] + red[7];
  float mu = s1 * (1.f / DM);
  float var = s2 * (1.f / DM) - mu * mu;
  float rs = rsqrtf(var + 1e-5f);
  float t[3];
#pragma unroll
  for (int i = 0; i < 3; i++) {
    int c = tid + i * 256;
    t[i] = (v[i] - mu) * rs * w[c] + bb[c];
  }
  if (!ADA) {
#pragma unroll
    for (int i = 0; i < 3; i++) out[(size_t)row * DM + tid + i * 256] = t[i];
    return;
  }
  __syncthreads();
  s1 = t[0] + t[1] + t[2];
  s2 = t[0]*t[0] + t[1]*t[1] + t[2]*t[2];
#pragma unroll
  for (int o = 32; o > 0; o >>= 1) { s1 += __shfl_down(s1, o); s2 += __shfl_down(s2, o); }
  if (ln == 0) { red[wv*2] = s1; red[wv*2+1] = s2; }
  __syncthreads();
  s1 = red[0] + red[2] + red[4] + red[6];
  s2 = red[1] + red[3] + red[5] + red[7];
  float mu2 = s1 * (1.f / DM);
  float var2 = s2 * (1.f / DM) - mu2 * mu2;
  float rs2 = rsqrtf(var2 + 1e-5f);
#pragma unroll
  for (int i = 0; i < 3; i++) {
    int c = tid + i * 256;
    float sc = ss[bt * (2 * DM) + c];
    float sh = ss[bt * (2 * DM) + DM + c];
    float r = (t[i] - mu2) * rs2 * (1.f + sc) + sh;
    out[(size_t)row * DM + c] = r;
    outb[(size_t)row * DM + c] = f2bf(r);
  }
}

// adaln precompute
__global__ __launch_bounds__(256) void adaln_pre_k(const float* __restrict__ cond,
                                                   const float* __restrict__ aw,
                                                   const float* __restrict__ ab,
                                                   float* __restrict__ ss) {
  int idx = blockIdx.x * 256 + threadIdx.x;
  int e = idx % (2 * DM);
  int b = (idx / (2 * DM)) % BATCH;
  int l = idx / (BATCH * 2 * DM);
  const float* c = cond + b * 128;
  const float* wp = aw + ((size_t)l * (2 * DM) + e) * 128;
  float s = ab[l * (2 * DM) + e];
  for (int k = 0; k < 128; k++) s = fmaf(c[k], wp[k], s);
  ss[idx] = s;
}

extern "C" void kernel_launch(void* const* d_in, const int* in_sizes, int n_in,
                              void* d_out, int out_size, void* d_ws, size_t ws_size,
                              hipStream_t stream) {
  const float* x      = (const float*)d_in[0];
  const float* cond   = (const float*)d_in[1];
  const float* in_w   = (const float*)d_in[2];
  const float* conv_w = (const float*)d_in[3];
  const float* conv_b = (const float*)d_in[4];
  const float* xp_w   = (const float*)d_in[5];
  const float* dtp_w  = (const float*)d_in[6];
  const float* dtp_b  = (const float*)d_in[7];
  const float* A_log  = (const float*)d_in[8];
  const float* Dsk    = (const float*)d_in[9];
  const float* out_w  = (const float*)d_in[10];
  const float* norm_w = (const float*)d_in[11];
  const float* norm_b = (const float*)d_in[12];
  const float* ada_w  = (const float*)d_in[13];
  const float* ada_b  = (const float*)d_in[14];
  const float* fn_w   = (const float*)d_in[15];
  const float* fn_b   = (const float*)d_in[16];

  float* out_h = (float*)d_out;
  float* out_states = out_h + (size_t)NTOK * DM;

  float* p = (float*)d_ws;
  float* h_cur = p; p += (size_t)NTOK * DM;
  float* dbc   = p; p += (size_t)NTOK * DBC;
  float* res2  = p; p += (size_t)NTOK * DM;
  float* cumA  = p; p += (size_t)NCHUNK * BATCH * DI * DS;
  float* hloc  = p; p += (size_t)NCHUNK * BATCH * DI * DS;
  float* hin   = p; p += (size_t)NCHUNK * BATCH * DI * DS;
  float* ss    = p; p += (size_t)NL * BATCH * 2 * DM;
  float* xpart = p; p += (size_t)XKS * NTOK * DBC;
  float* negA  = p; p += (size_t)NL * DI * DS;
  float* cumdt = p; p += (size_t)NTOK * DI;          // fallback only
  unsigned short* q = (unsigned short*)p;
  unsigned short* in_w_bf  = q; q += (size_t)NL * 2 * DI * DM;
  unsigned short* out_w_bf = q; q += (size_t)NL * DM * DI;
  unsigned short* xp_w_bf  = q; q += (size_t)NL * DBC * DI;
  unsigned short* dtw_bf   = q; q += (size_t)NL * DI * 64;
  unsigned short* h_bf     = q; q += (size_t)NTOK * DM;
  unsigned short* xz_bf    = q; q += (size_t)NTOK * 2 * DI;
  unsigned short* xc_bf    = q; q += (size_t)NTOK * DI;
  unsigned short* dtb_bf   = q; q += (size_t)NTOK * DI;
  unsigned short* yb_bf    = q; q += (size_t)NTOK * DI;
  unsigned short* yloc_bf  = q; q += (size_t)NTOK * DI;  // fallback only
  unsigned short* dtA_bf   = q; q += (size_t)NTOK * 64;

  hipMemcpyAsync(h_cur, x, (size_t)NTOK * DM * sizeof(float),
                 hipMemcpyDeviceToDevice, stream);
  adaln_pre_k<<<72, 256, 0, stream>>>(cond, ada_w, ada_b, ss);
  cvtall_k<<<2048, 256, 0, stream>>>(x, in_w, out_w, xp_w,
                                     h_bf, in_w_bf, out_w_bf, xp_w_bf);
  misc_pre_k<<<(NL * 1536 * 64 + NL * DI * DS + 255) / 256, 256, 0, stream>>>(
      dtp_w, A_log, dtw_bf, negA);

  for (int l = 0; l < NL; l++) {
    // in_proj -> xz (bf16)
    bt128b_k<<<dim3(24, 16), 256, 0, stream>>>(
        h_bf, DM, in_w_bf + (size_t)l * 2 * DI * DM, DM, xz_bf, 2 * DI, DM);
    // conv + silu -> xc (bf16)
    conv_silu_k<<<dim3(DI / 256, SEQ / 16, BATCH), 256, 0, stream>>>(
        xz_bf, conv_w + (size_t)l * DI * 4, conv_b + (size_t)l * DI, xc_bf);
    // x_proj split-K
    xp_k<<<dim3(XKS, NTOK / 64), 256, 0, stream>>>(
        xc_bf, xp_w_bf + (size_t)l * DBC * DI, xpart);
    xp_reduce_k<<<NTOK * DBC / 4 / 256, 256, 0, stream>>>(xpart, dbc, dtA_bf);
    // dt_proj + softplus -> dtb (bf16)
    bt64_k<1><<<dim3(DI / 64, NTOK / 64), 256, 0, stream>>>(
        dtA_bf, 64, dtw_bf + (size_t)l * DI * 64, 64, dtb_bf, DI,
        64, dtp_b + (size_t)l * DI, nullptr);
    // fused scan (cooperative); fall back to 3-kernel path if launch rejected
    {
      const unsigned short* a0 = dtb_bf;
      const unsigned short* a1 = xc_bf;
      const float* a2 = dbc;
      const unsigned short* a3 = xz_bf;
      const float* a4 = negA + (size_t)l * DI * DS;
      const float* a5 = Dsk + (size_t)l * DI;
      float* a6 = cumA;
      float* a7 = hloc;
      float* a8 = hin;
      float* a9 = out_states + (size_t)l * BATCH * DI * DS;
      unsigned short* a10 = yb_bf;
      void* args[] = {&a0, &a1, &a2, &a3, &a4, &a5, &a6, &a7, &a8, &a9, &a10};
      hipError_t ce = hipLaunchCooperativeKernel((void*)scanfused_k,
                                                 dim3(NCHUNK, 12), dim3(256),
                                                 args, 0, stream);
      if (ce != hipSuccess) {
        scan1_k<<<dim3(NCHUNK, 12), 256, 0, stream>>>(
            dtb_bf, xc_bf, dbc, negA + (size_t)l * DI * DS, cumA, hloc,
            yloc_bf, cumdt);
        scan2_k<<<192, 256, 0, stream>>>(
            cumA, hloc, hin, out_states + (size_t)l * BATCH * DI * DS);
        scanfix_k<<<NTOK * DI / 256, 256, 0, stream>>>(
            yloc_bf, cumdt, xc_bf, xz_bf, dbc, negA + (size_t)l * DI * DS,
            Dsk + (size_t)l * DI, hin, yb_bf);
      }
    }
    // out_proj + residual
    bt64_k<2><<<dim3(DM / 64, NTOK / 64), 256, 0, stream>>>(
        yb_bf, DI, out_w_bf + (size_t)l * DM * DI, DI, res2, DM,
        DI, nullptr, h_cur);
    // LN + adaln modulate
    ln_k<true><<<NTOK, 256, 0, stream>>>(
        res2, norm_w + (size_t)l * DM, norm_b + (size_t)l * DM,
        ss + (size_t)l * BATCH * 2 * DM, h_cur, h_bf);
  }
  ln_k<false><<<NTOK, 256, 0, stream>>>(h_cur, fn_w, fn_b, nullptr, out_h, nullptr);
}

// Round 10
// 786.903 us; speedup vs baseline: 3.4758x; 3.4758x over previous
//
#include <hip/hip_runtime.h>
#include <hip/hip_bf16.h>

#define NL 6
#define DM 768
#define DI 1536
#define DS 16
#define NRANK 48
#define DBC 80
#define BATCH 2
#define SEQ 1024
#define NTOK (BATCH*SEQ)
#define NCHUNK 64
#define CHLEN 16
#define XKS 8
#define XKC (DI/XKS)

typedef __attribute__((ext_vector_type(8))) short short8;
typedef __attribute__((ext_vector_type(4))) float f32x4;
typedef __attribute__((ext_vector_type(4))) unsigned short ushort4v;

__device__ inline unsigned short f2bf(float f) {
  union { float f; unsigned u; } x; x.f = f;
  unsigned r = x.u + 0x7FFF + ((x.u >> 16) & 1);
  return (unsigned short)(r >> 16);
}
__device__ inline float bf2f(unsigned short s) {
  union { unsigned u; float f; } x; x.u = ((unsigned)s) << 16;
  return x.f;
}

__device__ inline void gl_lds16(const unsigned short* g, unsigned short* l) {
  __builtin_amdgcn_global_load_lds(
      (const __attribute__((address_space(1))) unsigned int*)(g),
      (__attribute__((address_space(3))) unsigned int*)(l),
      16, 0, 0);
}

// spans (in f32x4 chunks)
#define SPAN_X   (NTOK * DM / 4)
#define SPAN_INW (NL * 2 * DI * DM / 4)
#define SPAN_OUW (NL * DM * DI / 4)
#define SPAN_XPW (NL * DBC * DI / 4)
#define SPAN_ALL (SPAN_X + SPAN_INW + SPAN_OUW + SPAN_XPW)

__device__ inline void cvt4_store(const float* s, unsigned short* d, int i) {
  f32x4 v = ((const f32x4*)s)[i];
  union { ushort4v u4; __hip_bfloat162 h[2]; } u;
  float2 p;
  p.x = v[0]; p.y = v[1]; u.h[0] = __float22bfloat162_rn(p);
  p.x = v[2]; p.y = v[3]; u.h[1] = __float22bfloat162_rn(p);
  ((ushort4v*)d)[i] = u.u4;
}

// convert x (also fp32 copy -> h_cur), in_w, out_w, xp_w to bf16
__global__ __launch_bounds__(256) void cvtall_k(const float* __restrict__ x,
                                                const float* __restrict__ inw,
                                                const float* __restrict__ ouw,
                                                const float* __restrict__ xpw,
                                                unsigned short* __restrict__ xb,
                                                unsigned short* __restrict__ inwb,
                                                unsigned short* __restrict__ ouwb,
                                                unsigned short* __restrict__ xpwb,
                                                float* __restrict__ hc) {
  for (int i = blockIdx.x * 256 + threadIdx.x; i < SPAN_ALL; i += gridDim.x * 256) {
    if (i < SPAN_X) {
      f32x4 v = ((const f32x4*)x)[i];
      ((f32x4*)hc)[i] = v;
      union { ushort4v u4; __hip_bfloat162 h[2]; } u;
      float2 p;
      p.x = v[0]; p.y = v[1]; u.h[0] = __float22bfloat162_rn(p);
      p.x = v[2]; p.y = v[3]; u.h[1] = __float22bfloat162_rn(p);
      ((ushort4v*)xb)[i] = u.u4;
    }
    else if (i < SPAN_X + SPAN_INW) cvt4_store(inw, inwb, i - SPAN_X);
    else if (i < SPAN_X + SPAN_INW + SPAN_OUW) cvt4_store(ouw, ouwb, i - SPAN_X - SPAN_INW);
    else cvt4_store(xpw, xpwb, i - SPAN_X - SPAN_INW - SPAN_OUW);
  }
}

// misc: dtp_w pad->bf16 [NL][1536][64] + negA = -exp(A_log)
__global__ __launch_bounds__(256) void misc_pre_k(const float* __restrict__ w,
                                                  const float* __restrict__ al,
                                                  unsigned short* __restrict__ wb,
                                                  float* __restrict__ na) {
  int idx = blockIdx.x * 256 + threadIdx.x;
  const int NDT = NL * 1536 * 64;
  if (idx < NDT) {
    int col = idx & 63;
    int row = idx >> 6;
    wb[idx] = (col < NRANK) ? f2bf(w[(size_t)row * NRANK + col]) : (unsigned short)0;
  } else if (idx < NDT + NL * DI * DS) {
    int k = idx - NDT;
    na[k] = -__expf(al[k]);
  }
}

// ---------------------------------------------------------------------------
// 128x128-tile bf16 GEMM -> bf16 output (in_proj). gl_lds + double buffer.
// ---------------------------------------------------------------------------
__global__ __launch_bounds__(256) void bt128b_k(
    const unsigned short* __restrict__ A, int lda,
    const unsigned short* __restrict__ W, int ldw,
    unsigned short* __restrict__ C, int ldc,
    int K) {
  __shared__ __align__(16) unsigned short As[2][128 * 32];
  __shared__ __align__(16) unsigned short Ws[2][128 * 32];
  const int tid = threadIdx.x;
  const int bm = blockIdx.y * 128;
  const int bn = blockIdx.x * 128;
  const int lane = tid & 63;
  const int wv = tid >> 6;
  const int wm = (wv >> 1) * 64;
  const int wn = (wv & 1) * 64;
  const int fr = lane & 15;
  const int fs = lane >> 4;

  const int r0 = tid >> 2;
  const int s0 = (tid & 3) ^ (r0 & 3);

  const unsigned short* gA0 = A + (size_t)(bm + r0) * lda + s0 * 8;
  const unsigned short* gA1 = A + (size_t)(bm + r0 + 64) * lda + s0 * 8;
  const unsigned short* gW0 = W + (size_t)(bn + r0) * ldw + s0 * 8;
  const unsigned short* gW1 = W + (size_t)(bn + r0 + 64) * ldw + s0 * 8;

  f32x4 acc[4][4];
#pragma unroll
  for (int i = 0; i < 4; i++)
#pragma unroll
    for (int j = 0; j < 4; j++) acc[i][j] = (f32x4){0.f, 0.f, 0.f, 0.f};

  gl_lds16(gA0, &As[0][0] + tid * 8);
  gl_lds16(gA1, &As[0][2048] + tid * 8);
  gl_lds16(gW0, &Ws[0][0] + tid * 8);
  gl_lds16(gW1, &Ws[0][2048] + tid * 8);
  __syncthreads();

  const int nk = K >> 5;
  int buf = 0;
  for (int kk = 0; kk < nk; kk++) {
    if (kk + 1 < nk) {
      const int k0 = (kk + 1) * 32;
      gl_lds16(gA0 + k0, &As[buf ^ 1][0] + tid * 8);
      gl_lds16(gA1 + k0, &As[buf ^ 1][2048] + tid * 8);
      gl_lds16(gW0 + k0, &Ws[buf ^ 1][0] + tid * 8);
      gl_lds16(gW1 + k0, &Ws[buf ^ 1][2048] + tid * 8);
    }

    short8 af[4], bf[4];
#pragma unroll
    for (int i = 0; i < 4; i++) {
      int rowa = wm + i * 16 + fr;
      af[i] = *(const short8*)&As[buf][rowa * 32 + ((fs ^ (rowa & 3)) * 8)];
      int rowb = wn + i * 16 + fr;
      bf[i] = *(const short8*)&Ws[buf][rowb * 32 + ((fs ^ (rowb & 3)) * 8)];
    }
#pragma unroll
    for (int i = 0; i < 4; i++)
#pragma unroll
      for (int j = 0; j < 4; j++)
        acc[i][j] = __builtin_amdgcn_mfma_f32_16x16x32_bf16(af[i], bf[j], acc[i][j], 0, 0, 0);

    __syncthreads();
    buf ^= 1;
  }

#pragma unroll
  for (int i = 0; i < 4; i++) {
#pragma unroll
    for (int j = 0; j < 4; j++) {
#pragma unroll
      for (int r = 0; r < 4; r++) {
        int row = bm + wm + i * 16 + fs * 4 + r;
        int col = bn + wn + j * 16 + fr;
        C[(size_t)row * ldc + col] = f2bf(acc[i][j][r]);
      }
    }
  }
}

// ---------------------------------------------------------------------------
// 64x64-tile bf16 GEMM. EPI 1: softplus(v+bias)->bf16. EPI 2: fp32 v+resid.
// ---------------------------------------------------------------------------
template<int EPI>
__global__ __launch_bounds__(256) void bt64_k(
    const unsigned short* __restrict__ A, int lda,
    const unsigned short* __restrict__ W, int ldw,
    void* __restrict__ Cv, int ldc,
    int K,
    const float* __restrict__ bias,
    const float* __restrict__ resid) {
  __shared__ __align__(16) unsigned short As[2][64 * 32];
  __shared__ __align__(16) unsigned short Ws[2][64 * 32];
  const int tid = threadIdx.x;
  const int bm = blockIdx.y * 64;
  const int bn = blockIdx.x * 64;
  const int lane = tid & 63;
  const int wv = tid >> 6;
  const int wm = (wv >> 1) * 32;
  const int wn = (wv & 1) * 32;
  const int fr = lane & 15;
  const int fs = lane >> 4;

  const int r0 = tid >> 2;
  const int s0 = (tid & 3) ^ (r0 & 3);

  const unsigned short* gA = A + (size_t)(bm + r0) * lda + s0 * 8;
  const unsigned short* gW = W + (size_t)(bn + r0) * ldw + s0 * 8;

  f32x4 acc[2][2];
#pragma unroll
  for (int i = 0; i < 2; i++)
#pragma unroll
    for (int j = 0; j < 2; j++) acc[i][j] = (f32x4){0.f, 0.f, 0.f, 0.f};

  gl_lds16(gA, &As[0][0] + tid * 8);
  gl_lds16(gW, &Ws[0][0] + tid * 8);
  __syncthreads();

  const int nk = K >> 5;
  int buf = 0;
  for (int kk = 0; kk < nk; kk++) {
    if (kk + 1 < nk) {
      const int k0 = (kk + 1) * 32;
      gl_lds16(gA + k0, &As[buf ^ 1][0] + tid * 8);
      gl_lds16(gW + k0, &Ws[buf ^ 1][0] + tid * 8);
    }

    short8 af[2], bf[2];
#pragma unroll
    for (int i = 0; i < 2; i++) {
      int rowa = wm + i * 16 + fr;
      af[i] = *(const short8*)&As[buf][rowa * 32 + ((fs ^ (rowa & 3)) * 8)];
      int rowb = wn + i * 16 + fr;
      bf[i] = *(const short8*)&Ws[buf][rowb * 32 + ((fs ^ (rowb & 3)) * 8)];
    }
#pragma unroll
    for (int i = 0; i < 2; i++)
#pragma unroll
      for (int j = 0; j < 2; j++)
        acc[i][j] = __builtin_amdgcn_mfma_f32_16x16x32_bf16(af[i], bf[j], acc[i][j], 0, 0, 0);

    __syncthreads();
    buf ^= 1;
  }

#pragma unroll
  for (int i = 0; i < 2; i++) {
#pragma unroll
    for (int j = 0; j < 2; j++) {
#pragma unroll
      for (int r = 0; r < 4; r++) {
        int row = bm + wm + i * 16 + fs * 4 + r;
        int col = bn + wn + j * 16 + fr;
        float v = acc[i][j][r];
        if (EPI == 1) {
          float xv = v + bias[col];
          float sp = (xv > 20.f) ? xv : log1pf(__expf(xv));
          ((unsigned short*)Cv)[(size_t)row * ldc + col] = f2bf(sp);
        }
        if (EPI == 2) {
          ((float*)Cv)[(size_t)row * ldc + col] = v + resid[(size_t)row * ldc + col];
        }
      }
    }
  }
}

// ---------------------------------------------------------------------------
// x_proj split-K, bf16
// ---------------------------------------------------------------------------
__global__ __launch_bounds__(256) void xp_k(
    const unsigned short* __restrict__ A,
    const unsigned short* __restrict__ W,
    float* __restrict__ part) {
  __shared__ __align__(16) unsigned short As[64][40];
  __shared__ __align__(16) unsigned short Ws[80][40];
  const int tid = threadIdx.x;
  const int ks = blockIdx.x;
  const int bm = blockIdx.y * 64;
  const int lane = tid & 63;
  const int wv = tid >> 6;
  const int fr = lane & 15;
  const int fs = lane >> 4;
  const int fk = fs * 8;

  const int ar = tid >> 2;
  const int ac = (tid & 3) * 8;
  const int k0base = ks * XKC;

  const unsigned short* gA  = A + (size_t)(bm + ar) * DI + k0base + ac;
  const unsigned short* gW0 = W + (size_t)ar * DI + k0base + ac;
  const unsigned short* gW1 = W + (size_t)(64 + ar) * DI + k0base + ac;

  f32x4 acc[5];
#pragma unroll
  for (int n = 0; n < 5; n++) acc[n] = (f32x4){0.f, 0.f, 0.f, 0.f};

  short8 aA, w0A, w1A;
  aA = *(const short8*)(gA);
  w0A = *(const short8*)(gW0);
  if (tid < 64) w1A = *(const short8*)(gW1);

  const int nk = XKC / 32;
  for (int kk = 0; kk < nk; kk++) {
    __syncthreads();
    *(short8*)&As[ar][ac] = aA;
    *(short8*)&Ws[ar][ac] = w0A;
    if (tid < 64) *(short8*)&Ws[64 + ar][ac] = w1A;
    __syncthreads();

    if (kk + 1 < nk) {
      const int k0 = (kk + 1) * 32;
      aA = *(const short8*)(gA + k0);
      w0A = *(const short8*)(gW0 + k0);
      if (tid < 64) w1A = *(const short8*)(gW1 + k0);
    }

    short8 af = *(const short8*)&As[wv * 16 + fr][fk];
#pragma unroll
    for (int n = 0; n < 5; n++) {
      short8 bf = *(const short8*)&Ws[n * 16 + fr][fk];
      acc[n] = __builtin_amdgcn_mfma_f32_16x16x32_bf16(af, bf, acc[n], 0, 0, 0);
    }
  }

#pragma unroll
  for (int n = 0; n < 5; n++) {
#pragma unroll
    for (int r = 0; r < 4; r++) {
      int row = bm + wv * 16 + fs * 4 + r;
      part[((size_t)ks * NTOK + row) * DBC + n * 16 + fr] = acc[n][r];
    }
  }
}

// sum XKS partials -> dbc (fp32) + bf16 zero-padded dt-input [m][64]
__global__ __launch_bounds__(256) void xp_reduce_k(const float* __restrict__ part,
                                                   float* __restrict__ dbc,
                                                   unsigned short* __restrict__ dtA) {
  int i = blockIdx.x * 256 + threadIdx.x;
  const f32x4* p4 = (const f32x4*)part;
  const int stride4 = NTOK * DBC / 4;
  f32x4 s = p4[i];
#pragma unroll
  for (int ks = 1; ks < XKS; ks++) {
    f32x4 v = p4[(size_t)ks * stride4 + i];
    s[0] += v[0]; s[1] += v[1]; s[2] += v[2]; s[3] += v[3];
  }
  ((f32x4*)dbc)[i] = s;
  int c4 = (i * 4) % DBC;
  int m = (i * 4) / DBC;
  if (c4 < 64) {
    union { ushort4v u4; __hip_bfloat162 h[2]; } u;
    if (c4 < NRANK) {
      float2 p;
      p.x = s[0]; p.y = s[1]; u.h[0] = __float22bfloat162_rn(p);
      p.x = s[2]; p.y = s[3]; u.h[1] = __float22bfloat162_rn(p);
    } else {
      u.u4 = (ushort4v){0, 0, 0, 0};
    }
    *(ushort4v*)&dtA[(size_t)m * 64 + c4] = u.u4;
  }
}

// depthwise causal conv(4) + bias + silu, register-carry; bf16 in/out
__global__ __launch_bounds__(256) void conv_silu_k(const unsigned short* __restrict__ xz,
                                                   const float* __restrict__ cw,
                                                   const float* __restrict__ cb,
                                                   unsigned short* __restrict__ xcb) {
  const int d = blockIdx.x * 256 + threadIdx.x;
  const int l0 = blockIdx.y * 16;
  const int b = blockIdx.z;
  const size_t mbase = (size_t)b * SEQ;
  const float w0 = cw[d * 4 + 0], w1 = cw[d * 4 + 1];
  const float w2 = cw[d * 4 + 2], w3 = cw[d * 4 + 3];
  const float bias = cb[d];
  float c3 = (l0 >= 3) ? bf2f(xz[(mbase + l0 - 3) * (2 * DI) + d]) : 0.f;
  float c2 = (l0 >= 2) ? bf2f(xz[(mbase + l0 - 2) * (2 * DI) + d]) : 0.f;
  float c1 = (l0 >= 1) ? bf2f(xz[(mbase + l0 - 1) * (2 * DI) + d]) : 0.f;
#pragma unroll
  for (int t = 0; t < 16; t++) {
    const int l = l0 + t;
    float cur = bf2f(xz[(mbase + l) * (2 * DI) + d]);
    float s = bias + w0 * c3 + w1 * c2 + w2 * c1 + w3 * cur;
    float sig = 1.f / (1.f + __expf(-s));
    xcb[(mbase + l) * DI + d] = f2bf(s * sig);
    c3 = c2; c2 = c1; c1 = cur;
  }
}

// ---------------------------------------------------------------------------
// scan pass 1: local scan; cumA+hloc packed bf16x2 in one uint; yloc bf16;
// cumdt fp32.
// ---------------------------------------------------------------------------
__global__ __launch_bounds__(256) void scan1_k(const unsigned short* __restrict__ dt,
                                               const unsigned short* __restrict__ xc,
                                               const float* __restrict__ dbc,
                                               const float* __restrict__ negA_l,
                                               unsigned int* __restrict__ ch_pk,
                                               unsigned short* __restrict__ yloc,
                                               float* __restrict__ cumdt) {
  __shared__ float Bs[CHLEN][DS];
  __shared__ float Cs[CHLEN][DS];
  const int tid = threadIdx.x;
  const int j = blockIdx.x;
  const int cg = blockIdx.y;
  const int b = cg / 6;
  const int d = (cg % 6) * 256 + tid;
  const int c = b * DI + d;
  const int m0 = b * SEQ + j * CHLEN;

  for (int e = tid; e < CHLEN * 32; e += 256) {
    int row = e >> 5, col = e & 31;
    float v = dbc[(size_t)(m0 + row) * DBC + NRANK + col];
    if (col < DS) Bs[row][col] = v; else Cs[row][col - DS] = v;
  }

  float Av[DS];
  const float* na = negA_l + (size_t)d * DS;
#pragma unroll
  for (int s = 0; s < DS; s++) Av[s] = na[s];
  const float Av0 = Av[0];
  bool fast = true;
#pragma unroll
  for (int s = 0; s < DS; s++)
    fast = fast && (fabsf(Av[s] - (s + 1) * Av0) <= 1e-4f * (s + 1));

  float dts[CHLEN], xcs[CHLEN];
#pragma unroll
  for (int t = 0; t < CHLEN; t++) {
    dts[t] = bf2f(dt[(size_t)(m0 + t) * DI + d]);
    xcs[t] = bf2f(xc[(size_t)(m0 + t) * DI + d]);
  }
  __syncthreads();

  float h[DS];
#pragma unroll
  for (int s = 0; s < DS; s++) h[s] = 0.f;
  float cd = 0.f;

  for (int t = 0; t < CHLEN; t++) {
    float dtv = dts[t];
    cd += dtv;
    float dtx = dtv * xcs[t];
    float ysum = 0.f;
    if (fast) {
      float e1 = __expf(dtv * Av0);
      float dA = e1;
      h[0] = fmaf(dA, h[0], dtx * Bs[t][0]);
      ysum = fmaf(h[0], Cs[t][0], ysum);
#pragma unroll
      for (int s = 1; s < DS; s++) {
        dA *= e1;
        h[s] = fmaf(dA, h[s], dtx * Bs[t][s]);
        ysum = fmaf(h[s], Cs[t][s], ysum);
      }
    } else {
#pragma unroll
      for (int s = 0; s < DS; s++) {
        float dA = __expf(dtv * Av[s]);
        h[s] = fmaf(dA, h[s], dtx * Bs[t][s]);
        ysum = fmaf(h[s], Cs[t][s], ysum);
      }
    }
    size_t mi = (size_t)(m0 + t) * DI + d;
    yloc[mi] = f2bf(ysum);
    cumdt[mi] = cd;
  }

  size_t base = ((size_t)j * (BATCH * DI) + c) * DS;
#pragma unroll
  for (int s = 0; s < DS; s++) {
    unsigned int pk = (unsigned int)f2bf(__expf(cd * Av[s]))
                    | ((unsigned int)f2bf(h[s]) << 16);
    ch_pk[base + s] = pk;
  }
}

// pass 2: sequential chunk combine (packed bf16 io; states fp32)
__global__ __launch_bounds__(256) void scan2_k(const unsigned int* __restrict__ ch_pk,
                                               unsigned short* __restrict__ hin,
                                               float* __restrict__ states_out) {
  int idx = blockIdx.x * 256 + threadIdx.x;
  const int stride = BATCH * DI * DS;
  float h = 0.f;
  for (int j = 0; j < NCHUNK; j++) {
    hin[(size_t)j * stride + idx] = f2bf(h);
    unsigned int pk = ch_pk[(size_t)j * stride + idx];
    float ca = bf2f((unsigned short)(pk & 0xFFFF));
    float hl = bf2f((unsigned short)(pk >> 16));
    h = fmaf(ca, h, hl);
  }
  states_out[idx] = h;
}

// pass 3: parallel fixup (hin bf16)
__global__ __launch_bounds__(256) void scanfix_k(const unsigned short* __restrict__ yloc,
                                                 const float* __restrict__ cumdt,
                                                 const unsigned short* __restrict__ xc,
                                                 const unsigned short* __restrict__ xz,
                                                 const float* __restrict__ dbc,
                                                 const float* __restrict__ negA_l,
                                                 const float* __restrict__ Dsk,
                                                 const unsigned short* __restrict__ hin,
                                                 unsigned short* __restrict__ y) {
  int idx = blockIdx.x * 256 + threadIdx.x;
  int d = idx % DI;
  int m = idx / DI;
  int b = m / SEQ;
  int j = (m % SEQ) / CHLEN;
  float cd = cumdt[idx];
  float yv = bf2f(yloc[idx]);
  const f32x4* na4 = (const f32x4*)(negA_l + (size_t)d * DS);
  const f32x4* cp4 = (const f32x4*)(dbc + (size_t)m * DBC + NRANK + DS);
  const ushort4v* h4 = (const ushort4v*)(hin + ((size_t)j * (BATCH * DI) + (size_t)b * DI + d) * DS);
  float corr = 0.f;
#pragma unroll
  for (int q = 0; q < 4; q++) {
    f32x4 na = na4[q], cp = cp4[q];
    ushort4v hh = h4[q];
#pragma unroll
    for (int e = 0; e < 4; e++)
      corr = fmaf(__expf(cd * na[e]) * bf2f(hh[e]), cp[e], corr);
  }
  yv += corr;
  float xv = bf2f(xc[idx]);
  float zv = bf2f(xz[(size_t)m * (2 * DI) + DI + d]);
  float sig = 1.f / (1.f + __expf(-zv));
  y[idx] = f2bf((yv + Dsk[d] * xv) * (zv * sig));
}

// LN (w,b) then optionally LN_noaffine + adaln modulate
template<bool ADA>
__global__ __launch_bounds__(256) void ln_k(const float* __restrict__ in,
                                            const float* __restrict__ w,
                                            const float* __restrict__ bb,
                                            const float* __restrict__ ss,
                                            float* __restrict__ out,
                                            unsigned short* __restrict__ outb) {
  __shared__ float red[8];
  const int row = blockIdx.x;
  const int bt = row / SEQ;
  const int tid = threadIdx.x;
  const float* x = in + (size_t)row * DM;
  float v[3];
#pragma unroll
  for (int i = 0; i < 3; i++) v[i] = x[tid + i * 256];
  float s1 = v[0] + v[1] + v[2];
  float s2 = v[0]*v[0] + v[1]*v[1] + v[2]*v[2];
#pragma unroll
  for (int o = 32; o > 0; o >>= 1) { s1 += __shfl_down(s1, o); s2 += __shfl_down(s2, o); }
  int wv = tid >> 6, ln = tid & 63;
  if (ln == 0) { red[wv*2] = s1; red[wv*2+1] = s2; }
  __syncthreads();
  s1 = red[0] + red[2] + red[4] + red[6];
  s2 = red[1] + red[3] + red[5] + red[7];
  float mu = s1 * (1.f / DM);
  float var = s2 * (1.f / DM) - mu * mu;
  float rs = rsqrtf(var + 1e-5f);
  float t[3];
#pragma unroll
  for (int i = 0; i < 3; i++) {
    int c = tid + i * 256;
    t[i] = (v[i] - mu) * rs * w[c] + bb[c];
  }
  if (!ADA) {
#pragma unroll
    for (int i = 0; i < 3; i++) out[(size_t)row * DM + tid + i * 256] = t[i];
    return;
  }
  __syncthreads();
  s1 = t[0] + t[1] + t[2];
  s2 = t[0]*t[0] + t[1]*t[1] + t[2]*t[2];
#pragma unroll
  for (int o = 32; o > 0; o >>= 1) { s1 += __shfl_down(s1, o); s2 += __shfl_down(s2, o); }
  if (ln == 0) { red[wv*2] = s1; red[wv*2+1] = s2; }
  __syncthreads();
  s1 = red[0] + red[2] + red[4] + red[6];
  s2 = red[1] + red[3] + red[5] + red[7];
  float mu2 = s1 * (1.f / DM);
  float var2 = s2 * (1.f / DM) - mu2 * mu2;
  float rs2 = rsqrtf(var2 + 1e-5f);
#pragma unroll
  for (int i = 0; i < 3; i++) {
    int c = tid + i * 256;
    float sc = ss[bt * (2 * DM) + c];
    float sh = ss[bt * (2 * DM) + DM + c];
    float r = (t[i] - mu2) * rs2 * (1.f + sc) + sh;
    out[(size_t)row * DM + c] = r;
    outb[(size_t)row * DM + c] = f2bf(r);
  }
}

// adaln precompute
__global__ __launch_bounds__(256) void adaln_pre_k(const float* __restrict__ cond,
                                                   const float* __restrict__ aw,
                                                   const float* __restrict__ ab,
                                                   float* __restrict__ ss) {
  int idx = blockIdx.x * 256 + threadIdx.x;
  int e = idx % (2 * DM);
  int b = (idx / (2 * DM)) % BATCH;
  int l = idx / (BATCH * 2 * DM);
  const float* c = cond + b * 128;
  const float* wp = aw + ((size_t)l * (2 * DM) + e) * 128;
  float s = ab[l * (2 * DM) + e];
  for (int k = 0; k < 128; k++) s = fmaf(c[k], wp[k], s);
  ss[idx] = s;
}

extern "C" void kernel_launch(void* const* d_in, const int* in_sizes, int n_in,
                              void* d_out, int out_size, void* d_ws, size_t ws_size,
                              hipStream_t stream) {
  const float* x      = (const float*)d_in[0];
  const float* cond   = (const float*)d_in[1];
  const float* in_w   = (const float*)d_in[2];
  const float* conv_w = (const float*)d_in[3];
  const float* conv_b = (const float*)d_in[4];
  const float* xp_w   = (const float*)d_in[5];
  const float* dtp_w  = (const float*)d_in[6];
  const float* dtp_b  = (const float*)d_in[7];
  const float* A_log  = (const float*)d_in[8];
  const float* Dsk    = (const float*)d_in[9];
  const float* out_w  = (const float*)d_in[10];
  const float* norm_w = (const float*)d_in[11];
  const float* norm_b = (const float*)d_in[12];
  const float* ada_w  = (const float*)d_in[13];
  const float* ada_b  = (const float*)d_in[14];
  const float* fn_w   = (const float*)d_in[15];
  const float* fn_b   = (const float*)d_in[16];

  float* out_h = (float*)d_out;
  float* out_states = out_h + (size_t)NTOK * DM;

  float* p = (float*)d_ws;
  float* h_cur = p; p += (size_t)NTOK * DM;
  float* dbc   = p; p += (size_t)NTOK * DBC;
  float* res2  = p; p += (size_t)NTOK * DM;
  float* ss    = p; p += (size_t)NL * BATCH * 2 * DM;
  float* xpart = p; p += (size_t)XKS * NTOK * DBC;
  float* negA  = p; p += (size_t)NL * DI * DS;
  float* cumdt = p; p += (size_t)NTOK * DI;
  unsigned int* ch_pk = (unsigned int*)p; p += (size_t)NCHUNK * BATCH * DI * DS;
  unsigned short* q = (unsigned short*)p;
  unsigned short* hin      = q; q += (size_t)NCHUNK * BATCH * DI * DS;
  unsigned short* in_w_bf  = q; q += (size_t)NL * 2 * DI * DM;
  unsigned short* out_w_bf = q; q += (size_t)NL * DM * DI;
  unsigned short* xp_w_bf  = q; q += (size_t)NL * DBC * DI;
  unsigned short* dtw_bf   = q; q += (size_t)NL * DI * 64;
  unsigned short* h_bf     = q; q += (size_t)NTOK * DM;
  unsigned short* xz_bf    = q; q += (size_t)NTOK * 2 * DI;
  unsigned short* xc_bf    = q; q += (size_t)NTOK * DI;
  unsigned short* dtb_bf   = q; q += (size_t)NTOK * DI;
  unsigned short* yb_bf    = q; q += (size_t)NTOK * DI;
  unsigned short* yloc_bf  = q; q += (size_t)NTOK * DI;
  unsigned short* dtA_bf   = q; q += (size_t)NTOK * 64;

  adaln_pre_k<<<72, 256, 0, stream>>>(cond, ada_w, ada_b, ss);
  cvtall_k<<<2048, 256, 0, stream>>>(x, in_w, out_w, xp_w,
                                     h_bf, in_w_bf, out_w_bf, xp_w_bf, h_cur);
  misc_pre_k<<<(NL * 1536 * 64 + NL * DI * DS + 255) / 256, 256, 0, stream>>>(
      dtp_w, A_log, dtw_bf, negA);

  for (int l = 0; l < NL; l++) {
    // in_proj -> xz (bf16)
    bt128b_k<<<dim3(24, 16), 256, 0, stream>>>(
        h_bf, DM, in_w_bf + (size_t)l * 2 * DI * DM, DM, xz_bf, 2 * DI, DM);
    // conv + silu -> xc (bf16)
    conv_silu_k<<<dim3(DI / 256, SEQ / 16, BATCH), 256, 0, stream>>>(
        xz_bf, conv_w + (size_t)l * DI * 4, conv_b + (size_t)l * DI, xc_bf);
    // x_proj split-K
    xp_k<<<dim3(XKS, NTOK / 64), 256, 0, stream>>>(
        xc_bf, xp_w_bf + (size_t)l * DBC * DI, xpart);
    xp_reduce_k<<<NTOK * DBC / 4 / 256, 256, 0, stream>>>(xpart, dbc, dtA_bf);
    // dt_proj + softplus -> dtb (bf16)
    bt64_k<1><<<dim3(DI / 64, NTOK / 64), 256, 0, stream>>>(
        dtA_bf, 64, dtw_bf + (size_t)l * DI * 64, 64, dtb_bf, DI,
        64, dtp_b + (size_t)l * DI, nullptr);
    // scan trio
    scan1_k<<<dim3(NCHUNK, 12), 256, 0, stream>>>(
        dtb_bf, xc_bf, dbc, negA + (size_t)l * DI * DS, ch_pk, yloc_bf, cumdt);
    scan2_k<<<192, 256, 0, stream>>>(
        ch_pk, hin, out_states + (size_t)l * BATCH * DI * DS);
    scanfix_k<<<NTOK * DI / 256, 256, 0, stream>>>(
        yloc_bf, cumdt, xc_bf, xz_bf, dbc, negA + (size_t)l * DI * DS,
        Dsk + (size_t)l * DI, hin, yb_bf);
    // out_proj + residual
    bt64_k<2><<<dim3(DM / 64, NTOK / 64), 256, 0, stream>>>(
        yb_bf, DI, out_w_bf + (size_t)l * DM * DI, DI, res2, DM,
        DI, nullptr, h_cur);
    // LN + adaln modulate
    ln_k<true><<<NTOK, 256, 0, stream>>>(
        res2, norm_w + (size_t)l * DM, norm_b + (size_t)l * DM,
        ss + (size_t)l * BATCH * 2 * DM, h_cur, h_bf);
  }
  ln_k<false><<<NTOK, 256, 0, stream>>>(h_cur, fn_w, fn_b, nullptr, out_h, nullptr);
}

// Round 11
// 754.889 us; speedup vs baseline: 3.6232x; 1.0424x over previous
//
#include <hip/hip_runtime.h>
#include <hip/hip_bf16.h>

#define NL 6
#define DM 768
#define DI 1536
#define DS 16
#define NRANK 48
#define DBC 80
#define BATCH 2
#define SEQ 1024
#define NTOK (BATCH*SEQ)
#define NCHUNK 64
#define CHLEN 16
#define XKS 8
#define XKC (DI/XKS)

typedef __attribute__((ext_vector_type(8))) short short8;
typedef __attribute__((ext_vector_type(4))) float f32x4;
typedef __attribute__((ext_vector_type(4))) unsigned short ushort4v;

__device__ inline unsigned short f2bf(float f) {
  union { float f; unsigned u; } x; x.f = f;
  unsigned r = x.u + 0x7FFF + ((x.u >> 16) & 1);
  return (unsigned short)(r >> 16);
}
__device__ inline float bf2f(unsigned short s) {
  union { unsigned u; float f; } x; x.u = ((unsigned)s) << 16;
  return x.f;
}

__device__ inline void gl_lds16(const unsigned short* g, unsigned short* l) {
  __builtin_amdgcn_global_load_lds(
      (const __attribute__((address_space(1))) unsigned int*)(g),
      (__attribute__((address_space(3))) unsigned int*)(l),
      16, 0, 0);
}

// setup ranges (unit = 4 elements except ADA = 1 elem)
#define U_X   (NTOK * DM / 4)
#define U_INW (NL * 2 * DI * DM / 4)
#define U_OUW (NL * DM * DI / 4)
#define U_XPW (NL * DBC * DI / 4)
#define U_DTW (NL * DI * 64 / 4)
#define U_NA  (NL * DI * DS / 4)
#define U_DTA (NTOK * 64 / 4)
#define U_ADA (NL * BATCH * 2 * DM)
#define U_ALL (U_X + U_INW + U_OUW + U_XPW + U_DTW + U_NA + U_DTA + U_ADA)

__device__ inline void cvt4_store(const float* s, unsigned short* d, int i) {
  f32x4 v = ((const f32x4*)s)[i];
  union { ushort4v u4; __hip_bfloat162 h[2]; } u;
  float2 p;
  p.x = v[0]; p.y = v[1]; u.h[0] = __float22bfloat162_rn(p);
  p.x = v[2]; p.y = v[3]; u.h[1] = __float22bfloat162_rn(p);
  ((ushort4v*)d)[i] = u.u4;
}

// one setup kernel: x (fp32 copy + bf16), weights->bf16, dtw pad, negA,
// dtA zero-pad, adaln ss
__global__ __launch_bounds__(256) void setup_k(
    const float* __restrict__ x, const float* __restrict__ inw,
    const float* __restrict__ ouw, const float* __restrict__ xpw,
    const float* __restrict__ dtpw, const float* __restrict__ alog,
    const float* __restrict__ cond, const float* __restrict__ adaw,
    const float* __restrict__ adab,
    unsigned short* __restrict__ xb, unsigned short* __restrict__ inwb,
    unsigned short* __restrict__ ouwb, unsigned short* __restrict__ xpwb,
    unsigned short* __restrict__ dtwb, float* __restrict__ na,
    unsigned short* __restrict__ dtA, float* __restrict__ ss,
    float* __restrict__ hc) {
  for (int i = blockIdx.x * 256 + threadIdx.x; i < U_ALL; i += gridDim.x * 256) {
    int k = i;
    if (k < U_X) {
      f32x4 v = ((const f32x4*)x)[k];
      ((f32x4*)hc)[k] = v;
      union { ushort4v u4; __hip_bfloat162 h[2]; } u;
      float2 p;
      p.x = v[0]; p.y = v[1]; u.h[0] = __float22bfloat162_rn(p);
      p.x = v[2]; p.y = v[3]; u.h[1] = __float22bfloat162_rn(p);
      ((ushort4v*)xb)[k] = u.u4;
      continue;
    }
    k -= U_X;
    if (k < U_INW) { cvt4_store(inw, inwb, k); continue; }
    k -= U_INW;
    if (k < U_OUW) { cvt4_store(ouw, ouwb, k); continue; }
    k -= U_OUW;
    if (k < U_XPW) { cvt4_store(xpw, xpwb, k); continue; }
    k -= U_XPW;
    if (k < U_DTW) {
      int col4 = (k & 15) * 4;
      int row = k >> 4;
      ushort4v u4;
      if (col4 < NRANK) {
        const float* src = dtpw + (size_t)row * NRANK + col4;
        u4[0] = f2bf(src[0]); u4[1] = f2bf(src[1]);
        u4[2] = f2bf(src[2]); u4[3] = f2bf(src[3]);
      } else {
        u4 = (ushort4v){0, 0, 0, 0};
      }
      *(ushort4v*)&dtwb[(size_t)row * 64 + col4] = u4;
      continue;
    }
    k -= U_DTW;
    if (k < U_NA) {
      f32x4 v = ((const f32x4*)alog)[k];
      f32x4 r;
#pragma unroll
      for (int e = 0; e < 4; e++) r[e] = -__expf(v[e]);
      ((f32x4*)na)[k] = r;
      continue;
    }
    k -= U_NA;
    if (k < U_DTA) {
      ((ushort4v*)dtA)[k] = (ushort4v){0, 0, 0, 0};
      continue;
    }
    k -= U_DTA;
    {
      int e = k % (2 * DM);
      int b = (k / (2 * DM)) % BATCH;
      int l = k / (BATCH * 2 * DM);
      const float* c = cond + b * 128;
      const float* wp = adaw + ((size_t)l * (2 * DM) + e) * 128;
      float s = adab[l * (2 * DM) + e];
      for (int kk = 0; kk < 128; kk++) s = fmaf(c[kk], wp[kk], s);
      ss[k] = s;
    }
  }
}

// ---------------------------------------------------------------------------
// 128x128-tile bf16 GEMM -> bf16 output (in_proj). gl_lds + double buffer.
// ---------------------------------------------------------------------------
__global__ __launch_bounds__(256) void bt128b_k(
    const unsigned short* __restrict__ A, int lda,
    const unsigned short* __restrict__ W, int ldw,
    unsigned short* __restrict__ C, int ldc,
    int K) {
  __shared__ __align__(16) unsigned short As[2][128 * 32];
  __shared__ __align__(16) unsigned short Ws[2][128 * 32];
  const int tid = threadIdx.x;
  const int bm = blockIdx.y * 128;
  const int bn = blockIdx.x * 128;
  const int lane = tid & 63;
  const int wv = tid >> 6;
  const int wm = (wv >> 1) * 64;
  const int wn = (wv & 1) * 64;
  const int fr = lane & 15;
  const int fs = lane >> 4;

  const int r0 = tid >> 2;
  const int s0 = (tid & 3) ^ (r0 & 3);

  const unsigned short* gA0 = A + (size_t)(bm + r0) * lda + s0 * 8;
  const unsigned short* gA1 = A + (size_t)(bm + r0 + 64) * lda + s0 * 8;
  const unsigned short* gW0 = W + (size_t)(bn + r0) * ldw + s0 * 8;
  const unsigned short* gW1 = W + (size_t)(bn + r0 + 64) * ldw + s0 * 8;

  f32x4 acc[4][4];
#pragma unroll
  for (int i = 0; i < 4; i++)
#pragma unroll
    for (int j = 0; j < 4; j++) acc[i][j] = (f32x4){0.f, 0.f, 0.f, 0.f};

  gl_lds16(gA0, &As[0][0] + tid * 8);
  gl_lds16(gA1, &As[0][2048] + tid * 8);
  gl_lds16(gW0, &Ws[0][0] + tid * 8);
  gl_lds16(gW1, &Ws[0][2048] + tid * 8);
  __syncthreads();

  const int nk = K >> 5;
  int buf = 0;
  for (int kk = 0; kk < nk; kk++) {
    if (kk + 1 < nk) {
      const int k0 = (kk + 1) * 32;
      gl_lds16(gA0 + k0, &As[buf ^ 1][0] + tid * 8);
      gl_lds16(gA1 + k0, &As[buf ^ 1][2048] + tid * 8);
      gl_lds16(gW0 + k0, &Ws[buf ^ 1][0] + tid * 8);
      gl_lds16(gW1 + k0, &Ws[buf ^ 1][2048] + tid * 8);
    }

    short8 af[4], bf[4];
#pragma unroll
    for (int i = 0; i < 4; i++) {
      int rowa = wm + i * 16 + fr;
      af[i] = *(const short8*)&As[buf][rowa * 32 + ((fs ^ (rowa & 3)) * 8)];
      int rowb = wn + i * 16 + fr;
      bf[i] = *(const short8*)&Ws[buf][rowb * 32 + ((fs ^ (rowb & 3)) * 8)];
    }
#pragma unroll
    for (int i = 0; i < 4; i++)
#pragma unroll
      for (int j = 0; j < 4; j++)
        acc[i][j] = __builtin_amdgcn_mfma_f32_16x16x32_bf16(af[i], bf[j], acc[i][j], 0, 0, 0);

    __syncthreads();
    buf ^= 1;
  }

#pragma unroll
  for (int i = 0; i < 4; i++) {
#pragma unroll
    for (int j = 0; j < 4; j++) {
#pragma unroll
      for (int r = 0; r < 4; r++) {
        int row = bm + wm + i * 16 + fs * 4 + r;
        int col = bn + wn + j * 16 + fr;
        C[(size_t)row * ldc + col] = f2bf(acc[i][j][r]);
      }
    }
  }
}

// ---------------------------------------------------------------------------
// 64x64-tile bf16 GEMM. EPI 1: softplus(v+bias)->bf16. EPI 2: fp32 v+resid.
// ---------------------------------------------------------------------------
template<int EPI>
__global__ __launch_bounds__(256) void bt64_k(
    const unsigned short* __restrict__ A, int lda,
    const unsigned short* __restrict__ W, int ldw,
    void* __restrict__ Cv, int ldc,
    int K,
    const float* __restrict__ bias,
    const float* __restrict__ resid) {
  __shared__ __align__(16) unsigned short As[2][64 * 32];
  __shared__ __align__(16) unsigned short Ws[2][64 * 32];
  const int tid = threadIdx.x;
  const int bm = blockIdx.y * 64;
  const int bn = blockIdx.x * 64;
  const int lane = tid & 63;
  const int wv = tid >> 6;
  const int wm = (wv >> 1) * 32;
  const int wn = (wv & 1) * 32;
  const int fr = lane & 15;
  const int fs = lane >> 4;

  const int r0 = tid >> 2;
  const int s0 = (tid & 3) ^ (r0 & 3);

  const unsigned short* gA = A + (size_t)(bm + r0) * lda + s0 * 8;
  const unsigned short* gW = W + (size_t)(bn + r0) * ldw + s0 * 8;

  f32x4 acc[2][2];
#pragma unroll
  for (int i = 0; i < 2; i++)
#pragma unroll
    for (int j = 0; j < 2; j++) acc[i][j] = (f32x4){0.f, 0.f, 0.f, 0.f};

  gl_lds16(gA, &As[0][0] + tid * 8);
  gl_lds16(gW, &Ws[0][0] + tid * 8);
  __syncthreads();

  const int nk = K >> 5;
  int buf = 0;
  for (int kk = 0; kk < nk; kk++) {
    if (kk + 1 < nk) {
      const int k0 = (kk + 1) * 32;
      gl_lds16(gA + k0, &As[buf ^ 1][0] + tid * 8);
      gl_lds16(gW + k0, &Ws[buf ^ 1][0] + tid * 8);
    }

    short8 af[2], bf[2];
#pragma unroll
    for (int i = 0; i < 2; i++) {
      int rowa = wm + i * 16 + fr;
      af[i] = *(const short8*)&As[buf][rowa * 32 + ((fs ^ (rowa & 3)) * 8)];
      int rowb = wn + i * 16 + fr;
      bf[i] = *(const short8*)&Ws[buf][rowb * 32 + ((fs ^ (rowb & 3)) * 8)];
    }
#pragma unroll
    for (int i = 0; i < 2; i++)
#pragma unroll
      for (int j = 0; j < 2; j++)
        acc[i][j] = __builtin_amdgcn_mfma_f32_16x16x32_bf16(af[i], bf[j], acc[i][j], 0, 0, 0);

    __syncthreads();
    buf ^= 1;
  }

#pragma unroll
  for (int i = 0; i < 2; i++) {
#pragma unroll
    for (int j = 0; j < 2; j++) {
#pragma unroll
      for (int r = 0; r < 4; r++) {
        int row = bm + wm + i * 16 + fs * 4 + r;
        int col = bn + wn + j * 16 + fr;
        float v = acc[i][j][r];
        if (EPI == 1) {
          float xv = v + bias[col];
          float sp = (xv > 20.f) ? xv : log1pf(__expf(xv));
          ((unsigned short*)Cv)[(size_t)row * ldc + col] = f2bf(sp);
        }
        if (EPI == 2) {
          ((float*)Cv)[(size_t)row * ldc + col] = v + resid[(size_t)row * ldc + col];
        }
      }
    }
  }
}

// ---------------------------------------------------------------------------
// x_proj split-K, bf16 in, bf16 partials out
// ---------------------------------------------------------------------------
__global__ __launch_bounds__(256) void xp_k(
    const unsigned short* __restrict__ A,
    const unsigned short* __restrict__ W,
    unsigned short* __restrict__ part) {
  __shared__ __align__(16) unsigned short As[64][40];
  __shared__ __align__(16) unsigned short Ws[80][40];
  const int tid = threadIdx.x;
  const int ks = blockIdx.x;
  const int bm = blockIdx.y * 64;
  const int lane = tid & 63;
  const int wv = tid >> 6;
  const int fr = lane & 15;
  const int fs = lane >> 4;
  const int fk = fs * 8;

  const int ar = tid >> 2;
  const int ac = (tid & 3) * 8;
  const int k0base = ks * XKC;

  const unsigned short* gA  = A + (size_t)(bm + ar) * DI + k0base + ac;
  const unsigned short* gW0 = W + (size_t)ar * DI + k0base + ac;
  const unsigned short* gW1 = W + (size_t)(64 + ar) * DI + k0base + ac;

  f32x4 acc[5];
#pragma unroll
  for (int n = 0; n < 5; n++) acc[n] = (f32x4){0.f, 0.f, 0.f, 0.f};

  short8 aA, w0A, w1A;
  aA = *(const short8*)(gA);
  w0A = *(const short8*)(gW0);
  if (tid < 64) w1A = *(const short8*)(gW1);

  const int nk = XKC / 32;
  for (int kk = 0; kk < nk; kk++) {
    __syncthreads();
    *(short8*)&As[ar][ac] = aA;
    *(short8*)&Ws[ar][ac] = w0A;
    if (tid < 64) *(short8*)&Ws[64 + ar][ac] = w1A;
    __syncthreads();

    if (kk + 1 < nk) {
      const int k0 = (kk + 1) * 32;
      aA = *(const short8*)(gA + k0);
      w0A = *(const short8*)(gW0 + k0);
      if (tid < 64) w1A = *(const short8*)(gW1 + k0);
    }

    short8 af = *(const short8*)&As[wv * 16 + fr][fk];
#pragma unroll
    for (int n = 0; n < 5; n++) {
      short8 bf = *(const short8*)&Ws[n * 16 + fr][fk];
      acc[n] = __builtin_amdgcn_mfma_f32_16x16x32_bf16(af, bf, acc[n], 0, 0, 0);
    }
  }

#pragma unroll
  for (int n = 0; n < 5; n++) {
#pragma unroll
    for (int r = 0; r < 4; r++) {
      int row = bm + wv * 16 + fs * 4 + r;
      part[((size_t)ks * NTOK + row) * DBC + n * 16 + fr] = f2bf(acc[n][r]);
    }
  }
}

// sum XKS bf16 partials -> dtA bf16 (cols 0..47) / bc bf16 (cols 48..79 -> 0..31)
__global__ __launch_bounds__(256) void xp_reduce_k(const unsigned short* __restrict__ part,
                                                   unsigned short* __restrict__ dtA,
                                                   unsigned short* __restrict__ bc) {
  int i = blockIdx.x * 256 + threadIdx.x;  // NTOK*DBC/4 = 40960
  const ushort4v* p4 = (const ushort4v*)part;
  const int stride4 = NTOK * DBC / 4;
  float s0 = 0.f, s1 = 0.f, s2 = 0.f, s3 = 0.f;
#pragma unroll
  for (int ks = 0; ks < XKS; ks++) {
    ushort4v v = p4[(size_t)ks * stride4 + i];
    s0 += bf2f(v[0]); s1 += bf2f(v[1]); s2 += bf2f(v[2]); s3 += bf2f(v[3]);
  }
  ushort4v o;
  o[0] = f2bf(s0); o[1] = f2bf(s1); o[2] = f2bf(s2); o[3] = f2bf(s3);
  int c4 = (i * 4) % DBC;
  int m = (i * 4) / DBC;
  if (c4 < NRANK) {
    *(ushort4v*)&dtA[(size_t)m * 64 + c4] = o;
  } else {
    *(ushort4v*)&bc[(size_t)m * 32 + (c4 - NRANK)] = o;
  }
}

// depthwise causal conv(4) + bias + silu, register-carry, ushort2 vectorized
__global__ __launch_bounds__(256) void conv_silu_k(const unsigned short* __restrict__ xz,
                                                   const float* __restrict__ cw,
                                                   const float* __restrict__ cb,
                                                   unsigned short* __restrict__ xcb) {
  const int d0 = (blockIdx.x * 256 + threadIdx.x) * 2;
  const int l0 = blockIdx.y * 16;
  const int b = blockIdx.z;
  const size_t mbase = (size_t)b * SEQ;
  const float wa0 = cw[d0 * 4 + 0], wa1 = cw[d0 * 4 + 1];
  const float wa2 = cw[d0 * 4 + 2], wa3 = cw[d0 * 4 + 3];
  const float wb0 = cw[d0 * 4 + 4], wb1 = cw[d0 * 4 + 5];
  const float wb2 = cw[d0 * 4 + 6], wb3 = cw[d0 * 4 + 7];
  const float ba = cb[d0], bb = cb[d0 + 1];

  float a3 = 0.f, a2 = 0.f, a1 = 0.f, b3 = 0.f, b2 = 0.f, b1 = 0.f;
  if (l0 >= 3) { ushort2 u = *(const ushort2*)&xz[(mbase + l0 - 3) * (2 * DI) + d0]; a3 = bf2f(u.x); b3 = bf2f(u.y); }
  if (l0 >= 2) { ushort2 u = *(const ushort2*)&xz[(mbase + l0 - 2) * (2 * DI) + d0]; a2 = bf2f(u.x); b2 = bf2f(u.y); }
  if (l0 >= 1) { ushort2 u = *(const ushort2*)&xz[(mbase + l0 - 1) * (2 * DI) + d0]; a1 = bf2f(u.x); b1 = bf2f(u.y); }
#pragma unroll
  for (int t = 0; t < 16; t++) {
    const int l = l0 + t;
    ushort2 u = *(const ushort2*)&xz[(mbase + l) * (2 * DI) + d0];
    float ca = bf2f(u.x), cbv = bf2f(u.y);
    float sa = ba + wa0 * a3 + wa1 * a2 + wa2 * a1 + wa3 * ca;
    float sb = bb + wb0 * b3 + wb1 * b2 + wb2 * b1 + wb3 * cbv;
    float ra = sa / (1.f + __expf(-sa));
    float rb = sb / (1.f + __expf(-sb));
    ushort2 o; o.x = f2bf(ra); o.y = f2bf(rb);
    *(ushort2*)&xcb[(mbase + l) * DI + d0] = o;
    a3 = a2; a2 = a1; a1 = ca;
    b3 = b2; b2 = b1; b1 = cbv;
  }
}

// ---------------------------------------------------------------------------
// scan pass 1: bf16 inputs; B/C from bf16 bc; outputs ch_pk (cumA|hloc bf16x2)
// and yc_pk (yloc|cumdt bf16x2)
// ---------------------------------------------------------------------------
__global__ __launch_bounds__(256) void scan1_k(const unsigned short* __restrict__ dt,
                                               const unsigned short* __restrict__ xc,
                                               const unsigned short* __restrict__ bc,
                                               const float* __restrict__ negA_l,
                                               unsigned int* __restrict__ ch_pk,
                                               unsigned int* __restrict__ yc_pk) {
  __shared__ float Bs[CHLEN][DS];
  __shared__ float Cs[CHLEN][DS];
  const int tid = threadIdx.x;
  const int j = blockIdx.x;
  const int cg = blockIdx.y;
  const int b = cg / 6;
  const int d = (cg % 6) * 256 + tid;
  const int c = b * DI + d;
  const int m0 = b * SEQ + j * CHLEN;

  for (int e = tid; e < CHLEN * 32; e += 256) {
    int row = e >> 5, col = e & 31;
    float v = bf2f(bc[(size_t)(m0 + row) * 32 + col]);
    if (col < DS) Bs[row][col] = v; else Cs[row][col - DS] = v;
  }

  float Av[DS];
  const float* na = negA_l + (size_t)d * DS;
#pragma unroll
  for (int s = 0; s < DS; s++) Av[s] = na[s];
  const float Av0 = Av[0];
  bool fast = true;
#pragma unroll
  for (int s = 0; s < DS; s++)
    fast = fast && (fabsf(Av[s] - (s + 1) * Av0) <= 1e-4f * (s + 1));

  float dts[CHLEN], xcs[CHLEN];
#pragma unroll
  for (int t = 0; t < CHLEN; t++) {
    dts[t] = bf2f(dt[(size_t)(m0 + t) * DI + d]);
    xcs[t] = bf2f(xc[(size_t)(m0 + t) * DI + d]);
  }
  __syncthreads();

  float h[DS];
#pragma unroll
  for (int s = 0; s < DS; s++) h[s] = 0.f;
  float cd = 0.f;

  for (int t = 0; t < CHLEN; t++) {
    float dtv = dts[t];
    cd += dtv;
    float dtx = dtv * xcs[t];
    float ysum = 0.f;
    if (fast) {
      float e1 = __expf(dtv * Av0);
      float dA = e1;
      h[0] = fmaf(dA, h[0], dtx * Bs[t][0]);
      ysum = fmaf(h[0], Cs[t][0], ysum);
#pragma unroll
      for (int s = 1; s < DS; s++) {
        dA *= e1;
        h[s] = fmaf(dA, h[s], dtx * Bs[t][s]);
        ysum = fmaf(h[s], Cs[t][s], ysum);
      }
    } else {
#pragma unroll
      for (int s = 0; s < DS; s++) {
        float dA = __expf(dtv * Av[s]);
        h[s] = fmaf(dA, h[s], dtx * Bs[t][s]);
        ysum = fmaf(h[s], Cs[t][s], ysum);
      }
    }
    yc_pk[(size_t)(m0 + t) * DI + d] =
        (unsigned int)f2bf(ysum) | ((unsigned int)f2bf(cd) << 16);
  }

  size_t base = ((size_t)j * (BATCH * DI) + c) * DS;
#pragma unroll
  for (int s = 0; s < DS; s++) {
    unsigned int pk = (unsigned int)f2bf(__expf(cd * Av[s]))
                    | ((unsigned int)f2bf(h[s]) << 16);
    ch_pk[base + s] = pk;
  }
}

// pass 2: sequential chunk combine (packed bf16 io; states fp32)
__global__ __launch_bounds__(256) void scan2_k(const unsigned int* __restrict__ ch_pk,
                                               unsigned short* __restrict__ hin,
                                               float* __restrict__ states_out) {
  int idx = blockIdx.x * 256 + threadIdx.x;
  const int stride = BATCH * DI * DS;
  float h = 0.f;
  for (int j = 0; j < NCHUNK; j++) {
    hin[(size_t)j * stride + idx] = f2bf(h);
    unsigned int pk = ch_pk[(size_t)j * stride + idx];
    float ca = bf2f((unsigned short)(pk & 0xFFFF));
    float hl = bf2f((unsigned short)(pk >> 16));
    h = fmaf(ca, h, hl);
  }
  states_out[idx] = h;
}

// pass 3: parallel fixup (packed yc, bf16 C and hin)
__global__ __launch_bounds__(256) void scanfix_k(const unsigned int* __restrict__ yc_pk,
                                                 const unsigned short* __restrict__ xc,
                                                 const unsigned short* __restrict__ xz,
                                                 const unsigned short* __restrict__ bc,
                                                 const float* __restrict__ negA_l,
                                                 const float* __restrict__ Dsk,
                                                 const unsigned short* __restrict__ hin,
                                                 unsigned short* __restrict__ y) {
  int idx = blockIdx.x * 256 + threadIdx.x;
  int d = idx % DI;
  int m = idx / DI;
  int b = m / SEQ;
  int j = (m % SEQ) / CHLEN;
  unsigned int pk = yc_pk[idx];
  float yv = bf2f((unsigned short)(pk & 0xFFFF));
  float cd = bf2f((unsigned short)(pk >> 16));
  const f32x4* na4 = (const f32x4*)(negA_l + (size_t)d * DS);
  const ushort4v* cp4 = (const ushort4v*)(bc + (size_t)m * 32 + DS);
  const ushort4v* h4 = (const ushort4v*)(hin + ((size_t)j * (BATCH * DI) + (size_t)b * DI + d) * DS);
  float corr = 0.f;
#pragma unroll
  for (int q = 0; q < 4; q++) {
    f32x4 na = na4[q];
    ushort4v cp = cp4[q];
    ushort4v hh = h4[q];
#pragma unroll
    for (int e = 0; e < 4; e++)
      corr = fmaf(__expf(cd * na[e]) * bf2f(hh[e]), bf2f(cp[e]), corr);
  }
  yv += corr;
  float xv = bf2f(xc[idx]);
  float zv = bf2f(xz[(size_t)m * (2 * DI) + DI + d]);
  float sig = 1.f / (1.f + __expf(-zv));
  y[idx] = f2bf((yv + Dsk[d] * xv) * (zv * sig));
}

// LN (w,b) then optionally LN_noaffine + adaln modulate
template<bool ADA>
__global__ __launch_bounds__(256) void ln_k(const float* __restrict__ in,
                                            const float* __restrict__ w,
                                            const float* __restrict__ bb,
                                            const float* __restrict__ ss,
                                            float* __restrict__ out,
                                            unsigned short* __restrict__ outb) {
  __shared__ float red[8];
  const int row = blockIdx.x;
  const int bt = row / SEQ;
  const int tid = threadIdx.x;
  const float* x = in + (size_t)row * DM;
  float v[3];
#pragma unroll
  for (int i = 0; i < 3; i++) v[i] = x[tid + i * 256];
  float s1 = v[0] + v[1] + v[2];
  float s2 = v[0]*v[0] + v[1]*v[1] + v[2]*v[2];
#pragma unroll
  for (int o = 32; o > 0; o >>= 1) { s1 += __shfl_down(s1, o); s2 += __shfl_down(s2, o); }
  int wv = tid >> 6, ln = tid & 63;
  if (ln == 0) { red[wv*2] = s1; red[wv*2+1] = s2; }
  __syncthreads();
  s1 = red[0] + red[2] + red[4] + red[6];
  s2 = red[1] + red[3] + red[5] + red[7];
  float mu = s1 * (1.f / DM);
  float var = s2 * (1.f / DM) - mu * mu;
  float rs = rsqrtf(var + 1e-5f);
  float t[3];
#pragma unroll
  for (int i = 0; i < 3; i++) {
    int c = tid + i * 256;
    t[i] = (v[i] - mu) * rs * w[c] + bb[c];
  }
  if (!ADA) {
#pragma unroll
    for (int i = 0; i < 3; i++) out[(size_t)row * DM + tid + i * 256] = t[i];
    return;
  }
  __syncthreads();
  s1 = t[0] + t[1] + t[2];
  s2 = t[0]*t[0] + t[1]*t[1] + t[2]*t[2];
#pragma unroll
  for (int o = 32; o > 0; o >>= 1) { s1 += __shfl_down(s1, o); s2 += __shfl_down(s2, o); }
  if (ln == 0) { red[wv*2] = s1; red[wv*2+1] = s2; }
  __syncthreads();
  s1 = red[0] + red[2] + red[4] + red[6];
  s2 = red[1] + red[3] + red[5] + red[7];
  float mu2 = s1 * (1.f / DM);
  float var2 = s2 * (1.f / DM) - mu2 * mu2;
  float rs2 = rsqrtf(var2 + 1e-5f);
#pragma unroll
  for (int i = 0; i < 3; i++) {
    int c = tid + i * 256;
    float sc = ss[bt * (2 * DM) + c];
    float sh = ss[bt * (2 * DM) + DM + c];
    float r = (t[i] - mu2) * rs2 * (1.f + sc) + sh;
    out[(size_t)row * DM + c] = r;
    outb[(size_t)row * DM + c] = f2bf(r);
  }
}

extern "C" void kernel_launch(void* const* d_in, const int* in_sizes, int n_in,
                              void* d_out, int out_size, void* d_ws, size_t ws_size,
                              hipStream_t stream) {
  const float* x      = (const float*)d_in[0];
  const float* cond   = (const float*)d_in[1];
  const float* in_w   = (const float*)d_in[2];
  const float* conv_w = (const float*)d_in[3];
  const float* conv_b = (const float*)d_in[4];
  const float* xp_w   = (const float*)d_in[5];
  const float* dtp_w  = (const float*)d_in[6];
  const float* dtp_b  = (const float*)d_in[7];
  const float* A_log  = (const float*)d_in[8];
  const float* Dsk    = (const float*)d_in[9];
  const float* out_w  = (const float*)d_in[10];
  const float* norm_w = (const float*)d_in[11];
  const float* norm_b = (const float*)d_in[12];
  const float* ada_w  = (const float*)d_in[13];
  const float* ada_b  = (const float*)d_in[14];
  const float* fn_w   = (const float*)d_in[15];
  const float* fn_b   = (const float*)d_in[16];

  float* out_h = (float*)d_out;
  float* out_states = out_h + (size_t)NTOK * DM;

  float* p = (float*)d_ws;
  float* h_cur = p; p += (size_t)NTOK * DM;
  float* res2  = p; p += (size_t)NTOK * DM;
  float* ss    = p; p += (size_t)NL * BATCH * 2 * DM;
  float* negA  = p; p += (size_t)NL * DI * DS;
  unsigned int* ch_pk = (unsigned int*)p; p += (size_t)NCHUNK * BATCH * DI * DS;
  unsigned int* yc_pk = (unsigned int*)p; p += (size_t)NTOK * DI;
  unsigned short* q = (unsigned short*)p;
  unsigned short* hin      = q; q += (size_t)NCHUNK * BATCH * DI * DS;
  unsigned short* in_w_bf  = q; q += (size_t)NL * 2 * DI * DM;
  unsigned short* out_w_bf = q; q += (size_t)NL * DM * DI;
  unsigned short* xp_w_bf  = q; q += (size_t)NL * DBC * DI;
  unsigned short* dtw_bf   = q; q += (size_t)NL * DI * 64;
  unsigned short* h_bf     = q; q += (size_t)NTOK * DM;
  unsigned short* xz_bf    = q; q += (size_t)NTOK * 2 * DI;
  unsigned short* xc_bf    = q; q += (size_t)NTOK * DI;
  unsigned short* dtb_bf   = q; q += (size_t)NTOK * DI;
  unsigned short* yb_bf    = q; q += (size_t)NTOK * DI;
  unsigned short* part_bf  = q; q += (size_t)XKS * NTOK * DBC;
  unsigned short* dtA_bf   = q; q += (size_t)NTOK * 64;
  unsigned short* bc_bf    = q; q += (size_t)NTOK * 32;

  setup_k<<<2048, 256, 0, stream>>>(x, in_w, out_w, xp_w, dtp_w, A_log,
                                    cond, ada_w, ada_b,
                                    h_bf, in_w_bf, out_w_bf, xp_w_bf, dtw_bf,
                                    negA, dtA_bf, ss, h_cur);

  for (int l = 0; l < NL; l++) {
    // in_proj -> xz (bf16)
    bt128b_k<<<dim3(24, 16), 256, 0, stream>>>(
        h_bf, DM, in_w_bf + (size_t)l * 2 * DI * DM, DM, xz_bf, 2 * DI, DM);
    // conv + silu -> xc (bf16), ushort2 vectorized
    conv_silu_k<<<dim3(DI / 512, SEQ / 16, BATCH), 256, 0, stream>>>(
        xz_bf, conv_w + (size_t)l * DI * 4, conv_b + (size_t)l * DI, xc_bf);
    // x_proj split-K (bf16 partials)
    xp_k<<<dim3(XKS, NTOK / 64), 256, 0, stream>>>(
        xc_bf, xp_w_bf + (size_t)l * DBC * DI, part_bf);
    xp_reduce_k<<<NTOK * DBC / 4 / 256, 256, 0, stream>>>(part_bf, dtA_bf, bc_bf);
    // dt_proj + softplus -> dtb (bf16)
    bt64_k<1><<<dim3(DI / 64, NTOK / 64), 256, 0, stream>>>(
        dtA_bf, 64, dtw_bf + (size_t)l * DI * 64, 64, dtb_bf, DI,
        64, dtp_b + (size_t)l * DI, nullptr);
    // scan trio
    scan1_k<<<dim3(NCHUNK, 12), 256, 0, stream>>>(
        dtb_bf, xc_bf, bc_bf, negA + (size_t)l * DI * DS, ch_pk, yc_pk);
    scan2_k<<<192, 256, 0, stream>>>(
        ch_pk, hin, out_states + (size_t)l * BATCH * DI * DS);
    scanfix_k<<<NTOK * DI / 256, 256, 0, stream>>>(
        yc_pk, xc_bf, xz_bf, bc_bf, negA + (size_t)l * DI * DS,
        Dsk + (size_t)l * DI, hin, yb_bf);
    // out_proj + residual
    bt64_k<2><<<dim3(DM / 64, NTOK / 64), 256, 0, stream>>>(
        yb_bf, DI, out_w_bf + (size_t)l * DM * DI, DI, res2, DM,
        DI, nullptr, h_cur);
    // LN + adaln modulate
    ln_k<true><<<NTOK, 256, 0, stream>>>(
        res2, norm_w + (size_t)l * DM, norm_b + (size_t)l * DM,
        ss + (size_t)l * BATCH * 2 * DM, h_cur, h_bf);
  }
  ln_k<false><<<NTOK, 256, 0, stream>>>(h_cur, fn_w, fn_b, nullptr, out_h, nullptr);
}

// Round 12
// 747.155 us; speedup vs baseline: 3.6607x; 1.0104x over previous
//
#include <hip/hip_runtime.h>
#include <hip/hip_bf16.h>

#define NL 6
#define DM 768
#define DI 1536
#define DS 16
#define NRANK 48
#define DBC 80
#define BATCH 2
#define SEQ 1024
#define NTOK (BATCH*SEQ)
#define NCHUNK 64
#define CHLEN 16
#define XKS 8
#define XKC (DI/XKS)

typedef __attribute__((ext_vector_type(8))) short short8;
typedef __attribute__((ext_vector_type(8))) unsigned short ushort8v;
typedef __attribute__((ext_vector_type(4))) float f32x4;
typedef __attribute__((ext_vector_type(4))) unsigned short ushort4v;

__device__ inline unsigned short f2bf(float f) {
  union { float f; unsigned u; } x; x.f = f;
  unsigned r = x.u + 0x7FFF + ((x.u >> 16) & 1);
  return (unsigned short)(r >> 16);
}
__device__ inline float bf2f(unsigned short s) {
  union { unsigned u; float f; } x; x.u = ((unsigned)s) << 16;
  return x.f;
}

__device__ inline void gl_lds16(const unsigned short* g, unsigned short* l) {
  __builtin_amdgcn_global_load_lds(
      (const __attribute__((address_space(1))) unsigned int*)(g),
      (__attribute__((address_space(3))) unsigned int*)(l),
      16, 0, 0);
}

// convert ranges, unit = 8 elements
#define V_X   (NTOK * DM / 8)
#define V_INW (NL * 2 * DI * DM / 8)
#define V_OUW (NL * DM * DI / 8)
#define V_XPW (NL * DBC * DI / 8)
#define V_DTW (NL * DI * 64 / 8)
#define V_NA  (NL * DI * DS / 8)
#define V_DTA (NTOK * 64 / 8)
#define V_ALL (V_X + V_INW + V_OUW + V_XPW + V_DTW + V_NA + V_DTA)

__device__ inline ushort8v cvt8v(f32x4 a, f32x4 b) {
  union { ushort8v u8; __hip_bfloat162 h[4]; } u;
  float2 p;
  p.x = a[0]; p.y = a[1]; u.h[0] = __float22bfloat162_rn(p);
  p.x = a[2]; p.y = a[3]; u.h[1] = __float22bfloat162_rn(p);
  p.x = b[0]; p.y = b[1]; u.h[2] = __float22bfloat162_rn(p);
  p.x = b[2]; p.y = b[3]; u.h[3] = __float22bfloat162_rn(p);
  return u.u8;
}
__device__ inline void cvt8_store(const float* s, unsigned short* d, int i) {
  f32x4 a = ((const f32x4*)s)[i * 2];
  f32x4 b = ((const f32x4*)s)[i * 2 + 1];
  ((ushort8v*)d)[i] = cvt8v(a, b);
}

// streaming conversions: x->bf16, weights->bf16, dtw pad, negA, dtA zero
__global__ __launch_bounds__(256) void cvt_k(
    const float* __restrict__ x, const float* __restrict__ inw,
    const float* __restrict__ ouw, const float* __restrict__ xpw,
    const float* __restrict__ dtpw, const float* __restrict__ alog,
    unsigned short* __restrict__ xb, unsigned short* __restrict__ inwb,
    unsigned short* __restrict__ ouwb, unsigned short* __restrict__ xpwb,
    unsigned short* __restrict__ dtwb, float* __restrict__ na,
    unsigned short* __restrict__ dtA) {
  for (int i = blockIdx.x * 256 + threadIdx.x; i < V_ALL; i += gridDim.x * 256) {
    int k = i;
    if (k < V_X) { cvt8_store(x, xb, k); continue; }
    k -= V_X;
    if (k < V_INW) { cvt8_store(inw, inwb, k); continue; }
    k -= V_INW;
    if (k < V_OUW) { cvt8_store(ouw, ouwb, k); continue; }
    k -= V_OUW;
    if (k < V_XPW) { cvt8_store(xpw, xpwb, k); continue; }
    k -= V_XPW;
    if (k < V_DTW) {
      int col8 = (k & 7) * 8;
      int row = k >> 3;
      ushort8v u8;
      if (col8 < NRANK) {
        const float* src = dtpw + (size_t)row * NRANK + col8;
        f32x4 a = *(const f32x4*)src;
        f32x4 b = *(const f32x4*)(src + 4);
        u8 = cvt8v(a, b);
      } else {
        u8 = (ushort8v){0,0,0,0,0,0,0,0};
      }
      *(ushort8v*)&dtwb[(size_t)row * 64 + col8] = u8;
      continue;
    }
    k -= V_DTW;
    if (k < V_NA) {
      f32x4 a = ((const f32x4*)alog)[k * 2];
      f32x4 b = ((const f32x4*)alog)[k * 2 + 1];
      f32x4 ra, rb;
#pragma unroll
      for (int e = 0; e < 4; e++) { ra[e] = -__expf(a[e]); rb[e] = -__expf(b[e]); }
      ((f32x4*)na)[k * 2] = ra;
      ((f32x4*)na)[k * 2 + 1] = rb;
      continue;
    }
    k -= V_NA;
    ((ushort8v*)dtA)[k] = (ushort8v){0,0,0,0,0,0,0,0};
  }
}

// adaln matvec: ss[l][b][e] = cond[b] . adaw[l][e] + adab[l][e]
__global__ __launch_bounds__(256) void ada_k(const float* __restrict__ cond,
                                             const float* __restrict__ aw,
                                             const float* __restrict__ ab,
                                             float* __restrict__ ss) {
  int idx = blockIdx.x * 256 + threadIdx.x;  // NL*BATCH*2*DM = 18432
  int e = idx % (2 * DM);
  int b = (idx / (2 * DM)) % BATCH;
  int l = idx / (BATCH * 2 * DM);
  const float* c = cond + b * 128;
  const float* wp = aw + ((size_t)l * (2 * DM) + e) * 128;
  float s = ab[l * (2 * DM) + e];
  for (int k = 0; k < 128; k++) s = fmaf(c[k], wp[k], s);
  ss[idx] = s;
}

// ---------------------------------------------------------------------------
// 128x128-tile bf16 GEMM -> bf16 out. 3-stage pipeline: counted vmcnt keeps
// 2 tiles in flight across raw s_barriers (no full drain per K-step).
// ---------------------------------------------------------------------------
__global__ __launch_bounds__(256) void bt128b_k(
    const unsigned short* __restrict__ A, int lda,
    const unsigned short* __restrict__ W, int ldw,
    unsigned short* __restrict__ C, int ldc,
    int K) {
  __shared__ __align__(16) unsigned short As[3][128 * 32];
  __shared__ __align__(16) unsigned short Ws[3][128 * 32];
  const int tid = threadIdx.x;
  const int bm = blockIdx.y * 128;
  const int bn = blockIdx.x * 128;
  const int lane = tid & 63;
  const int wv = tid >> 6;
  const int wm = (wv >> 1) * 64;
  const int wn = (wv & 1) * 64;
  const int fr = lane & 15;
  const int fs = lane >> 4;

  const int r0 = tid >> 2;
  const int s0 = (tid & 3) ^ (r0 & 3);

  const unsigned short* gA0 = A + (size_t)(bm + r0) * lda + s0 * 8;
  const unsigned short* gA1 = A + (size_t)(bm + r0 + 64) * lda + s0 * 8;
  const unsigned short* gW0 = W + (size_t)(bn + r0) * ldw + s0 * 8;
  const unsigned short* gW1 = W + (size_t)(bn + r0 + 64) * ldw + s0 * 8;

  f32x4 acc[4][4];
#pragma unroll
  for (int i = 0; i < 4; i++)
#pragma unroll
    for (int j = 0; j < 4; j++) acc[i][j] = (f32x4){0.f, 0.f, 0.f, 0.f};

  const int nk = K >> 5;
  // prologue: stage tiles 0,1
  gl_lds16(gA0, &As[0][0] + tid * 8);
  gl_lds16(gA1, &As[0][2048] + tid * 8);
  gl_lds16(gW0, &Ws[0][0] + tid * 8);
  gl_lds16(gW1, &Ws[0][2048] + tid * 8);
  if (nk > 1) {
    gl_lds16(gA0 + 32, &As[1][0] + tid * 8);
    gl_lds16(gA1 + 32, &As[1][2048] + tid * 8);
    gl_lds16(gW0 + 32, &Ws[1][0] + tid * 8);
    gl_lds16(gW1 + 32, &Ws[1][2048] + tid * 8);
  }

  for (int kk = 0; kk < nk; kk++) {
    const int b = kk % 3;
    if (kk + 2 < nk) {
      const int k0 = (kk + 2) * 32;
      const int nb = (kk + 2) % 3;
      gl_lds16(gA0 + k0, &As[nb][0] + tid * 8);
      gl_lds16(gA1 + k0, &As[nb][2048] + tid * 8);
      gl_lds16(gW0 + k0, &Ws[nb][0] + tid * 8);
      gl_lds16(gW1 + k0, &Ws[nb][2048] + tid * 8);
    }
    const int ahead = (nk - 1 - kk >= 2) ? 2 : (nk - 1 - kk);
    if (ahead == 2)      asm volatile("s_waitcnt vmcnt(8)" : : : "memory");
    else if (ahead == 1) asm volatile("s_waitcnt vmcnt(4)" : : : "memory");
    else                 asm volatile("s_waitcnt vmcnt(0)" : : : "memory");
    __builtin_amdgcn_s_barrier();
    __builtin_amdgcn_sched_barrier(0);

    short8 af[4], bf[4];
#pragma unroll
    for (int i = 0; i < 4; i++) {
      int rowa = wm + i * 16 + fr;
      af[i] = *(const short8*)&As[b][rowa * 32 + ((fs ^ (rowa & 3)) * 8)];
      int rowb = wn + i * 16 + fr;
      bf[i] = *(const short8*)&Ws[b][rowb * 32 + ((fs ^ (rowb & 3)) * 8)];
    }
#pragma unroll
    for (int i = 0; i < 4; i++)
#pragma unroll
      for (int j = 0; j < 4; j++)
        acc[i][j] = __builtin_amdgcn_mfma_f32_16x16x32_bf16(af[i], bf[j], acc[i][j], 0, 0, 0);

    __builtin_amdgcn_s_barrier();
  }

#pragma unroll
  for (int i = 0; i < 4; i++) {
#pragma unroll
    for (int j = 0; j < 4; j++) {
#pragma unroll
      for (int r = 0; r < 4; r++) {
        int row = bm + wm + i * 16 + fs * 4 + r;
        int col = bn + wn + j * 16 + fr;
        C[(size_t)row * ldc + col] = f2bf(acc[i][j][r]);
      }
    }
  }
}

// ---------------------------------------------------------------------------
// 64x64-tile bf16 GEMM, 3-stage pipeline. EPI 1: softplus->bf16. EPI 2: +resid.
// ---------------------------------------------------------------------------
template<int EPI>
__global__ __launch_bounds__(256) void bt64_k(
    const unsigned short* __restrict__ A, int lda,
    const unsigned short* __restrict__ W, int ldw,
    void* __restrict__ Cv, int ldc,
    int K,
    const float* __restrict__ bias,
    const float* __restrict__ resid) {
  __shared__ __align__(16) unsigned short As[3][64 * 32];
  __shared__ __align__(16) unsigned short Ws[3][64 * 32];
  const int tid = threadIdx.x;
  const int bm = blockIdx.y * 64;
  const int bn = blockIdx.x * 64;
  const int lane = tid & 63;
  const int wv = tid >> 6;
  const int wm = (wv >> 1) * 32;
  const int wn = (wv & 1) * 32;
  const int fr = lane & 15;
  const int fs = lane >> 4;

  const int r0 = tid >> 2;
  const int s0 = (tid & 3) ^ (r0 & 3);

  const unsigned short* gA = A + (size_t)(bm + r0) * lda + s0 * 8;
  const unsigned short* gW = W + (size_t)(bn + r0) * ldw + s0 * 8;

  f32x4 acc[2][2];
#pragma unroll
  for (int i = 0; i < 2; i++)
#pragma unroll
    for (int j = 0; j < 2; j++) acc[i][j] = (f32x4){0.f, 0.f, 0.f, 0.f};

  const int nk = K >> 5;
  gl_lds16(gA, &As[0][0] + tid * 8);
  gl_lds16(gW, &Ws[0][0] + tid * 8);
  if (nk > 1) {
    gl_lds16(gA + 32, &As[1][0] + tid * 8);
    gl_lds16(gW + 32, &Ws[1][0] + tid * 8);
  }

  for (int kk = 0; kk < nk; kk++) {
    const int b = kk % 3;
    if (kk + 2 < nk) {
      const int k0 = (kk + 2) * 32;
      const int nb = (kk + 2) % 3;
      gl_lds16(gA + k0, &As[nb][0] + tid * 8);
      gl_lds16(gW + k0, &Ws[nb][0] + tid * 8);
    }
    const int ahead = (nk - 1 - kk >= 2) ? 2 : (nk - 1 - kk);
    if (ahead == 2)      asm volatile("s_waitcnt vmcnt(4)" : : : "memory");
    else if (ahead == 1) asm volatile("s_waitcnt vmcnt(2)" : : : "memory");
    else                 asm volatile("s_waitcnt vmcnt(0)" : : : "memory");
    __builtin_amdgcn_s_barrier();
    __builtin_amdgcn_sched_barrier(0);

    short8 af[2], bf[2];
#pragma unroll
    for (int i = 0; i < 2; i++) {
      int rowa = wm + i * 16 + fr;
      af[i] = *(const short8*)&As[b][rowa * 32 + ((fs ^ (rowa & 3)) * 8)];
      int rowb = wn + i * 16 + fr;
      bf[i] = *(const short8*)&Ws[b][rowb * 32 + ((fs ^ (rowb & 3)) * 8)];
    }
#pragma unroll
    for (int i = 0; i < 2; i++)
#pragma unroll
      for (int j = 0; j < 2; j++)
        acc[i][j] = __builtin_amdgcn_mfma_f32_16x16x32_bf16(af[i], bf[j], acc[i][j], 0, 0, 0);

    __builtin_amdgcn_s_barrier();
  }

#pragma unroll
  for (int i = 0; i < 2; i++) {
#pragma unroll
    for (int j = 0; j < 2; j++) {
#pragma unroll
      for (int r = 0; r < 4; r++) {
        int row = bm + wm + i * 16 + fs * 4 + r;
        int col = bn + wn + j * 16 + fr;
        float v = acc[i][j][r];
        if (EPI == 1) {
          float xv = v + bias[col];
          float sp = (xv > 20.f) ? xv : log1pf(__expf(xv));
          ((unsigned short*)Cv)[(size_t)row * ldc + col] = f2bf(sp);
        }
        if (EPI == 2) {
          ((float*)Cv)[(size_t)row * ldc + col] = v + resid[(size_t)row * ldc + col];
        }
      }
    }
  }
}

// ---------------------------------------------------------------------------
// x_proj split-K, bf16 in, bf16 partials out
// ---------------------------------------------------------------------------
__global__ __launch_bounds__(256) void xp_k(
    const unsigned short* __restrict__ A,
    const unsigned short* __restrict__ W,
    unsigned short* __restrict__ part) {
  __shared__ __align__(16) unsigned short As[64][40];
  __shared__ __align__(16) unsigned short Ws[80][40];
  const int tid = threadIdx.x;
  const int ks = blockIdx.x;
  const int bm = blockIdx.y * 64;
  const int lane = tid & 63;
  const int wv = tid >> 6;
  const int fr = lane & 15;
  const int fs = lane >> 4;
  const int fk = fs * 8;

  const int ar = tid >> 2;
  const int ac = (tid & 3) * 8;
  const int k0base = ks * XKC;

  const unsigned short* gA  = A + (size_t)(bm + ar) * DI + k0base + ac;
  const unsigned short* gW0 = W + (size_t)ar * DI + k0base + ac;
  const unsigned short* gW1 = W + (size_t)(64 + ar) * DI + k0base + ac;

  f32x4 acc[5];
#pragma unroll
  for (int n = 0; n < 5; n++) acc[n] = (f32x4){0.f, 0.f, 0.f, 0.f};

  short8 aA, w0A, w1A;
  aA = *(const short8*)(gA);
  w0A = *(const short8*)(gW0);
  if (tid < 64) w1A = *(const short8*)(gW1);

  const int nk = XKC / 32;
  for (int kk = 0; kk < nk; kk++) {
    __syncthreads();
    *(short8*)&As[ar][ac] = aA;
    *(short8*)&Ws[ar][ac] = w0A;
    if (tid < 64) *(short8*)&Ws[64 + ar][ac] = w1A;
    __syncthreads();

    if (kk + 1 < nk) {
      const int k0 = (kk + 1) * 32;
      aA = *(const short8*)(gA + k0);
      w0A = *(const short8*)(gW0 + k0);
      if (tid < 64) w1A = *(const short8*)(gW1 + k0);
    }

    short8 af = *(const short8*)&As[wv * 16 + fr][fk];
#pragma unroll
    for (int n = 0; n < 5; n++) {
      short8 bf = *(const short8*)&Ws[n * 16 + fr][fk];
      acc[n] = __builtin_amdgcn_mfma_f32_16x16x32_bf16(af, bf, acc[n], 0, 0, 0);
    }
  }

#pragma unroll
  for (int n = 0; n < 5; n++) {
#pragma unroll
    for (int r = 0; r < 4; r++) {
      int row = bm + wv * 16 + fs * 4 + r;
      part[((size_t)ks * NTOK + row) * DBC + n * 16 + fr] = f2bf(acc[n][r]);
    }
  }
}

// sum XKS bf16 partials -> dtA bf16 (cols 0..47) / bc bf16 (cols 48..79 -> 0..31)
__global__ __launch_bounds__(256) void xp_reduce_k(const unsigned short* __restrict__ part,
                                                   unsigned short* __restrict__ dtA,
                                                   unsigned short* __restrict__ bc) {
  int i = blockIdx.x * 256 + threadIdx.x;
  const ushort4v* p4 = (const ushort4v*)part;
  const int stride4 = NTOK * DBC / 4;
  float s0 = 0.f, s1 = 0.f, s2 = 0.f, s3 = 0.f;
#pragma unroll
  for (int ks = 0; ks < XKS; ks++) {
    ushort4v v = p4[(size_t)ks * stride4 + i];
    s0 += bf2f(v[0]); s1 += bf2f(v[1]); s2 += bf2f(v[2]); s3 += bf2f(v[3]);
  }
  ushort4v o;
  o[0] = f2bf(s0); o[1] = f2bf(s1); o[2] = f2bf(s2); o[3] = f2bf(s3);
  int c4 = (i * 4) % DBC;
  int m = (i * 4) / DBC;
  if (c4 < NRANK) {
    *(ushort4v*)&dtA[(size_t)m * 64 + c4] = o;
  } else {
    *(ushort4v*)&bc[(size_t)m * 32 + (c4 - NRANK)] = o;
  }
}

// depthwise causal conv(4) + bias + silu, register-carry, ushort2 vectorized
__global__ __launch_bounds__(256) void conv_silu_k(const unsigned short* __restrict__ xz,
                                                   const float* __restrict__ cw,
                                                   const float* __restrict__ cb,
                                                   unsigned short* __restrict__ xcb) {
  const int d0 = (blockIdx.x * 256 + threadIdx.x) * 2;
  const int l0 = blockIdx.y * 16;
  const int b = blockIdx.z;
  const size_t mbase = (size_t)b * SEQ;
  const float wa0 = cw[d0 * 4 + 0], wa1 = cw[d0 * 4 + 1];
  const float wa2 = cw[d0 * 4 + 2], wa3 = cw[d0 * 4 + 3];
  const float wb0 = cw[d0 * 4 + 4], wb1 = cw[d0 * 4 + 5];
  const float wb2 = cw[d0 * 4 + 6], wb3 = cw[d0 * 4 + 7];
  const float ba = cb[d0], bb = cb[d0 + 1];

  float a3 = 0.f, a2 = 0.f, a1 = 0.f, b3 = 0.f, b2 = 0.f, b1 = 0.f;
  if (l0 >= 3) { ushort2 u = *(const ushort2*)&xz[(mbase + l0 - 3) * (2 * DI) + d0]; a3 = bf2f(u.x); b3 = bf2f(u.y); }
  if (l0 >= 2) { ushort2 u = *(const ushort2*)&xz[(mbase + l0 - 2) * (2 * DI) + d0]; a2 = bf2f(u.x); b2 = bf2f(u.y); }
  if (l0 >= 1) { ushort2 u = *(const ushort2*)&xz[(mbase + l0 - 1) * (2 * DI) + d0]; a1 = bf2f(u.x); b1 = bf2f(u.y); }
#pragma unroll
  for (int t = 0; t < 16; t++) {
    const int l = l0 + t;
    ushort2 u = *(const ushort2*)&xz[(mbase + l) * (2 * DI) + d0];
    float ca = bf2f(u.x), cbv = bf2f(u.y);
    float sa = ba + wa0 * a3 + wa1 * a2 + wa2 * a1 + wa3 * ca;
    float sb = bb + wb0 * b3 + wb1 * b2 + wb2 * b1 + wb3 * cbv;
    float ra = sa / (1.f + __expf(-sa));
    float rb = sb / (1.f + __expf(-sb));
    ushort2 o; o.x = f2bf(ra); o.y = f2bf(rb);
    *(ushort2*)&xcb[(mbase + l) * DI + d0] = o;
    a3 = a2; a2 = a1; a1 = ca;
    b3 = b2; b2 = b1; b1 = cbv;
  }
}

// ---------------------------------------------------------------------------
// scan pass 1: bf16 inputs; outputs ch_pk (cumA|hloc bf16x2), yc_pk (yloc|cumdt)
// ---------------------------------------------------------------------------
__global__ __launch_bounds__(256) void scan1_k(const unsigned short* __restrict__ dt,
                                               const unsigned short* __restrict__ xc,
                                               const unsigned short* __restrict__ bc,
                                               const float* __restrict__ negA_l,
                                               unsigned int* __restrict__ ch_pk,
                                               unsigned int* __restrict__ yc_pk) {
  __shared__ float Bs[CHLEN][DS];
  __shared__ float Cs[CHLEN][DS];
  const int tid = threadIdx.x;
  const int j = blockIdx.x;
  const int cg = blockIdx.y;
  const int b = cg / 6;
  const int d = (cg % 6) * 256 + tid;
  const int c = b * DI + d;
  const int m0 = b * SEQ + j * CHLEN;

  for (int e = tid; e < CHLEN * 32; e += 256) {
    int row = e >> 5, col = e & 31;
    float v = bf2f(bc[(size_t)(m0 + row) * 32 + col]);
    if (col < DS) Bs[row][col] = v; else Cs[row][col - DS] = v;
  }

  float Av[DS];
  const float* na = negA_l + (size_t)d * DS;
#pragma unroll
  for (int s = 0; s < DS; s++) Av[s] = na[s];
  const float Av0 = Av[0];
  bool fast = true;
#pragma unroll
  for (int s = 0; s < DS; s++)
    fast = fast && (fabsf(Av[s] - (s + 1) * Av0) <= 1e-4f * (s + 1));

  float dts[CHLEN], xcs[CHLEN];
#pragma unroll
  for (int t = 0; t < CHLEN; t++) {
    dts[t] = bf2f(dt[(size_t)(m0 + t) * DI + d]);
    xcs[t] = bf2f(xc[(size_t)(m0 + t) * DI + d]);
  }
  __syncthreads();

  float h[DS];
#pragma unroll
  for (int s = 0; s < DS; s++) h[s] = 0.f;
  float cd = 0.f;

  for (int t = 0; t < CHLEN; t++) {
    float dtv = dts[t];
    cd += dtv;
    float dtx = dtv * xcs[t];
    float ysum = 0.f;
    if (fast) {
      float e1 = __expf(dtv * Av0);
      float dA = e1;
      h[0] = fmaf(dA, h[0], dtx * Bs[t][0]);
      ysum = fmaf(h[0], Cs[t][0], ysum);
#pragma unroll
      for (int s = 1; s < DS; s++) {
        dA *= e1;
        h[s] = fmaf(dA, h[s], dtx * Bs[t][s]);
        ysum = fmaf(h[s], Cs[t][s], ysum);
      }
    } else {
#pragma unroll
      for (int s = 0; s < DS; s++) {
        float dA = __expf(dtv * Av[s]);
        h[s] = fmaf(dA, h[s], dtx * Bs[t][s]);
        ysum = fmaf(h[s], Cs[t][s], ysum);
      }
    }
    yc_pk[(size_t)(m0 + t) * DI + d] =
        (unsigned int)f2bf(ysum) | ((unsigned int)f2bf(cd) << 16);
  }

  size_t base = ((size_t)j * (BATCH * DI) + c) * DS;
#pragma unroll
  for (int s = 0; s < DS; s++) {
    unsigned int pk = (unsigned int)f2bf(__expf(cd * Av[s]))
                    | ((unsigned int)f2bf(h[s]) << 16);
    ch_pk[base + s] = pk;
  }
}

// pass 2: sequential chunk combine
__global__ __launch_bounds__(256) void scan2_k(const unsigned int* __restrict__ ch_pk,
                                               unsigned short* __restrict__ hin,
                                               float* __restrict__ states_out) {
  int idx = blockIdx.x * 256 + threadIdx.x;
  const int stride = BATCH * DI * DS;
  float h = 0.f;
  for (int j = 0; j < NCHUNK; j++) {
    hin[(size_t)j * stride + idx] = f2bf(h);
    unsigned int pk = ch_pk[(size_t)j * stride + idx];
    float ca = bf2f((unsigned short)(pk & 0xFFFF));
    float hl = bf2f((unsigned short)(pk >> 16));
    h = fmaf(ca, h, hl);
  }
  states_out[idx] = h;
}

// pass 3: parallel fixup
__global__ __launch_bounds__(256) void scanfix_k(const unsigned int* __restrict__ yc_pk,
                                                 const unsigned short* __restrict__ xc,
                                                 const unsigned short* __restrict__ xz,
                                                 const unsigned short* __restrict__ bc,
                                                 const float* __restrict__ negA_l,
                                                 const float* __restrict__ Dsk,
                                                 const unsigned short* __restrict__ hin,
                                                 unsigned short* __restrict__ y) {
  int idx = blockIdx.x * 256 + threadIdx.x;
  int d = idx % DI;
  int m = idx / DI;
  int b = m / SEQ;
  int j = (m % SEQ) / CHLEN;
  unsigned int pk = yc_pk[idx];
  float yv = bf2f((unsigned short)(pk & 0xFFFF));
  float cd = bf2f((unsigned short)(pk >> 16));
  const f32x4* na4 = (const f32x4*)(negA_l + (size_t)d * DS);
  const ushort4v* cp4 = (const ushort4v*)(bc + (size_t)m * 32 + DS);
  const ushort4v* h4 = (const ushort4v*)(hin + ((size_t)j * (BATCH * DI) + (size_t)b * DI + d) * DS);
  float corr = 0.f;
#pragma unroll
  for (int q = 0; q < 4; q++) {
    f32x4 na = na4[q];
    ushort4v cp = cp4[q];
    ushort4v hh = h4[q];
#pragma unroll
    for (int e = 0; e < 4; e++)
      corr = fmaf(__expf(cd * na[e]) * bf2f(hh[e]), bf2f(cp[e]), corr);
  }
  yv += corr;
  float xv = bf2f(xc[idx]);
  float zv = bf2f(xz[(size_t)m * (2 * DI) + DI + d]);
  float sig = 1.f / (1.f + __expf(-zv));
  y[idx] = f2bf((yv + Dsk[d] * xv) * (zv * sig));
}

// LN (w,b) then optionally LN_noaffine + adaln modulate
template<bool ADA>
__global__ __launch_bounds__(256) void ln_k(const float* __restrict__ in,
                                            const float* __restrict__ w,
                                            const float* __restrict__ bb,
                                            const float* __restrict__ ss,
                                            float* __restrict__ out,
                                            unsigned short* __restrict__ outb) {
  __shared__ float red[8];
  const int row = blockIdx.x;
  const int bt = row / SEQ;
  const int tid = threadIdx.x;
  const float* x = in + (size_t)row * DM;
  float v[3];
#pragma unroll
  for (int i = 0; i < 3; i++) v[i] = x[tid + i * 256];
  float s1 = v[0] + v[1] + v[2];
  float s2 = v[0]*v[0] + v[1]*v[1] + v[2]*v[2];
#pragma unroll
  for (int o = 32; o > 0; o >>= 1) { s1 += __shfl_down(s1, o); s2 += __shfl_down(s2, o); }
  int wv = tid >> 6, ln = tid & 63;
  if (ln == 0) { red[wv*2] = s1; red[wv*2+1] = s2; }
  __syncthreads();
  s1 = red[0] + red[2] + red[4] + red[6];
  s2 = red[1] + red[3] + red[5] + red[7];
  float mu = s1 * (1.f / DM);
  float var = s2 * (1.f / DM) - mu * mu;
  float rs = rsqrtf(var + 1e-5f);
  float t[3];
#pragma unroll
  for (int i = 0; i < 3; i++) {
    int c = tid + i * 256;
    t[i] = (v[i] - mu) * rs * w[c] + bb[c];
  }
  if (!ADA) {
#pragma unroll
    for (int i = 0; i < 3; i++) out[(size_t)row * DM + tid + i * 256] = t[i];
    return;
  }
  __syncthreads();
  s1 = t[0] + t[1] + t[2];
  s2 = t[0]*t[0] + t[1]*t[1] + t[2]*t[2];
#pragma unroll
  for (int o = 32; o > 0; o >>= 1) { s1 += __shfl_down(s1, o); s2 += __shfl_down(s2, o); }
  if (ln == 0) { red[wv*2] = s1; red[wv*2+1] = s2; }
  __syncthreads();
  s1 = red[0] + red[2] + red[4] + red[6];
  s2 = red[1] + red[3] + red[5] + red[7];
  float mu2 = s1 * (1.f / DM);
  float var2 = s2 * (1.f / DM) - mu2 * mu2;
  float rs2 = rsqrtf(var2 + 1e-5f);
#pragma unroll
  for (int i = 0; i < 3; i++) {
    int c = tid + i * 256;
    float sc = ss[bt * (2 * DM) + c];
    float sh = ss[bt * (2 * DM) + DM + c];
    float r = (t[i] - mu2) * rs2 * (1.f + sc) + sh;
    out[(size_t)row * DM + c] = r;
    outb[(size_t)row * DM + c] = f2bf(r);
  }
}

extern "C" void kernel_launch(void* const* d_in, const int* in_sizes, int n_in,
                              void* d_out, int out_size, void* d_ws, size_t ws_size,
                              hipStream_t stream) {
  const float* x      = (const float*)d_in[0];
  const float* cond   = (const float*)d_in[1];
  const float* in_w   = (const float*)d_in[2];
  const float* conv_w = (const float*)d_in[3];
  const float* conv_b = (const float*)d_in[4];
  const float* xp_w   = (const float*)d_in[5];
  const float* dtp_w  = (const float*)d_in[6];
  const float* dtp_b  = (const float*)d_in[7];
  const float* A_log  = (const float*)d_in[8];
  const float* Dsk    = (const float*)d_in[9];
  const float* out_w  = (const float*)d_in[10];
  const float* norm_w = (const float*)d_in[11];
  const float* norm_b = (const float*)d_in[12];
  const float* ada_w  = (const float*)d_in[13];
  const float* ada_b  = (const float*)d_in[14];
  const float* fn_w   = (const float*)d_in[15];
  const float* fn_b   = (const float*)d_in[16];

  float* out_h = (float*)d_out;
  float* out_states = out_h + (size_t)NTOK * DM;

  float* p = (float*)d_ws;
  float* h_cur = p; p += (size_t)NTOK * DM;
  float* res2  = p; p += (size_t)NTOK * DM;
  float* ss    = p; p += (size_t)NL * BATCH * 2 * DM;
  float* negA  = p; p += (size_t)NL * DI * DS;
  unsigned int* ch_pk = (unsigned int*)p; p += (size_t)NCHUNK * BATCH * DI * DS;
  unsigned int* yc_pk = (unsigned int*)p; p += (size_t)NTOK * DI;
  unsigned short* q = (unsigned short*)p;
  unsigned short* hin      = q; q += (size_t)NCHUNK * BATCH * DI * DS;
  unsigned short* in_w_bf  = q; q += (size_t)NL * 2 * DI * DM;
  unsigned short* out_w_bf = q; q += (size_t)NL * DM * DI;
  unsigned short* xp_w_bf  = q; q += (size_t)NL * DBC * DI;
  unsigned short* dtw_bf   = q; q += (size_t)NL * DI * 64;
  unsigned short* h_bf     = q; q += (size_t)NTOK * DM;
  unsigned short* xz_bf    = q; q += (size_t)NTOK * 2 * DI;
  unsigned short* xc_bf    = q; q += (size_t)NTOK * DI;
  unsigned short* dtb_bf   = q; q += (size_t)NTOK * DI;
  unsigned short* yb_bf    = q; q += (size_t)NTOK * DI;
  unsigned short* part_bf  = q; q += (size_t)XKS * NTOK * DBC;
  unsigned short* dtA_bf   = q; q += (size_t)NTOK * 64;
  unsigned short* bc_bf    = q; q += (size_t)NTOK * 32;

  cvt_k<<<2048, 256, 0, stream>>>(x, in_w, out_w, xp_w, dtp_w, A_log,
                                  h_bf, in_w_bf, out_w_bf, xp_w_bf, dtw_bf,
                                  negA, dtA_bf);
  ada_k<<<72, 256, 0, stream>>>(cond, ada_w, ada_b, ss);

  for (int l = 0; l < NL; l++) {
    // in_proj -> xz (bf16)
    bt128b_k<<<dim3(24, 16), 256, 0, stream>>>(
        h_bf, DM, in_w_bf + (size_t)l * 2 * DI * DM, DM, xz_bf, 2 * DI, DM);
    // conv + silu -> xc (bf16)
    conv_silu_k<<<dim3(DI / 512, SEQ / 16, BATCH), 256, 0, stream>>>(
        xz_bf, conv_w + (size_t)l * DI * 4, conv_b + (size_t)l * DI, xc_bf);
    // x_proj split-K (bf16 partials)
    xp_k<<<dim3(XKS, NTOK / 64), 256, 0, stream>>>(
        xc_bf, xp_w_bf + (size_t)l * DBC * DI, part_bf);
    xp_reduce_k<<<NTOK * DBC / 4 / 256, 256, 0, stream>>>(part_bf, dtA_bf, bc_bf);
    // dt_proj + softplus -> dtb (bf16)
    bt64_k<1><<<dim3(DI / 64, NTOK / 64), 256, 0, stream>>>(
        dtA_bf, 64, dtw_bf + (size_t)l * DI * 64, 64, dtb_bf, DI,
        64, dtp_b + (size_t)l * DI, nullptr);
    // scan trio
    scan1_k<<<dim3(NCHUNK, 12), 256, 0, stream>>>(
        dtb_bf, xc_bf, bc_bf, negA + (size_t)l * DI * DS, ch_pk, yc_pk);
    scan2_k<<<192, 256, 0, stream>>>(
        ch_pk, hin, out_states + (size_t)l * BATCH * DI * DS);
    scanfix_k<<<NTOK * DI / 256, 256, 0, stream>>>(
        yc_pk, xc_bf, xz_bf, bc_bf, negA + (size_t)l * DI * DS,
        Dsk + (size_t)l * DI, hin, yb_bf);
    // out_proj + residual (layer 0 residual comes straight from x)
    bt64_k<2><<<dim3(DM / 64, NTOK / 64), 256, 0, stream>>>(
        yb_bf, DI, out_w_bf + (size_t)l * DM * DI, DI, res2, DM,
        DI, nullptr, (l == 0) ? x : h_cur);
    // LN + adaln modulate
    ln_k<true><<<NTOK, 256, 0, stream>>>(
        res2, norm_w + (size_t)l * DM, norm_b + (size_t)l * DM,
        ss + (size_t)l * BATCH * 2 * DM, h_cur, h_bf);
  }
  ln_k<false><<<NTOK, 256, 0, stream>>>(h_cur, fn_w, fn_b, nullptr, out_h, nullptr);
}

// Round 13
// 696.877 us; speedup vs baseline: 3.9248x; 1.0721x over previous
//
#include <hip/hip_runtime.h>
#include <hip/hip_bf16.h>

#define NL 6
#define DM 768
#define DI 1536
#define DS 16
#define NRANK 48
#define DBC 80
#define BATCH 2
#define SEQ 1024
#define NTOK (BATCH*SEQ)
#define NCHUNK 64
#define CHLEN 16
#define XKS 8
#define XKC (DI/XKS)

typedef __attribute__((ext_vector_type(8))) short short8;
typedef __attribute__((ext_vector_type(8))) unsigned short ushort8v;
typedef __attribute__((ext_vector_type(4))) float f32x4;
typedef __attribute__((ext_vector_type(4))) unsigned short ushort4v;

__device__ inline unsigned short f2bf(float f) {
  union { float f; unsigned u; } x; x.f = f;
  unsigned r = x.u + 0x7FFF + ((x.u >> 16) & 1);
  return (unsigned short)(r >> 16);
}
__device__ inline float bf2f(unsigned short s) {
  union { unsigned u; float f; } x; x.u = ((unsigned)s) << 16;
  return x.f;
}

__device__ inline void gl_lds16(const unsigned short* g, unsigned short* l) {
  __builtin_amdgcn_global_load_lds(
      (const __attribute__((address_space(1))) unsigned int*)(g),
      (__attribute__((address_space(3))) unsigned int*)(l),
      16, 0, 0);
}

// convert ranges, unit = 8 elements; ADA tail unit = 1 element
#define V_X   (NTOK * DM / 8)
#define V_INW (NL * 2 * DI * DM / 8)
#define V_OUW (NL * DM * DI / 8)
#define V_XPW (NL * DBC * DI / 8)
#define V_DTW (NL * DI * 64 / 8)
#define V_NA  (NL * DI * DS / 8)
#define V_DTA (NTOK * 64 / 8)
#define V_ADA (NL * BATCH * 2 * DM)
#define V_ALL (V_X + V_INW + V_OUW + V_XPW + V_DTW + V_NA + V_DTA + V_ADA)

__device__ inline ushort8v cvt8v(f32x4 a, f32x4 b) {
  union { ushort8v u8; __hip_bfloat162 h[4]; } u;
  float2 p;
  p.x = a[0]; p.y = a[1]; u.h[0] = __float22bfloat162_rn(p);
  p.x = a[2]; p.y = a[3]; u.h[1] = __float22bfloat162_rn(p);
  p.x = b[0]; p.y = b[1]; u.h[2] = __float22bfloat162_rn(p);
  p.x = b[2]; p.y = b[3]; u.h[3] = __float22bfloat162_rn(p);
  return u.u8;
}
__device__ inline void cvt8_store(const float* s, unsigned short* d, int i) {
  f32x4 a = ((const f32x4*)s)[i * 2];
  f32x4 b = ((const f32x4*)s)[i * 2 + 1];
  ((ushort8v*)d)[i] = cvt8v(a, b);
}

// streaming conversions + adaln matvec tail
__global__ __launch_bounds__(256) void cvt_k(
    const float* __restrict__ x, const float* __restrict__ inw,
    const float* __restrict__ ouw, const float* __restrict__ xpw,
    const float* __restrict__ dtpw, const float* __restrict__ alog,
    const float* __restrict__ cond, const float* __restrict__ adaw,
    const float* __restrict__ adab,
    unsigned short* __restrict__ xb, unsigned short* __restrict__ inwb,
    unsigned short* __restrict__ ouwb, unsigned short* __restrict__ xpwb,
    unsigned short* __restrict__ dtwb, float* __restrict__ na,
    unsigned short* __restrict__ dtA, float* __restrict__ ss) {
  for (int i = blockIdx.x * 256 + threadIdx.x; i < V_ALL; i += gridDim.x * 256) {
    int k = i;
    if (k < V_X) { cvt8_store(x, xb, k); continue; }
    k -= V_X;
    if (k < V_INW) { cvt8_store(inw, inwb, k); continue; }
    k -= V_INW;
    if (k < V_OUW) { cvt8_store(ouw, ouwb, k); continue; }
    k -= V_OUW;
    if (k < V_XPW) { cvt8_store(xpw, xpwb, k); continue; }
    k -= V_XPW;
    if (k < V_DTW) {
      int col8 = (k & 7) * 8;
      int row = k >> 3;
      ushort8v u8;
      if (col8 < NRANK) {
        const float* src = dtpw + (size_t)row * NRANK + col8;
        f32x4 a = *(const f32x4*)src;
        f32x4 b = *(const f32x4*)(src + 4);
        u8 = cvt8v(a, b);
      } else {
        u8 = (ushort8v){0,0,0,0,0,0,0,0};
      }
      *(ushort8v*)&dtwb[(size_t)row * 64 + col8] = u8;
      continue;
    }
    k -= V_DTW;
    if (k < V_NA) {
      f32x4 a = ((const f32x4*)alog)[k * 2];
      f32x4 b = ((const f32x4*)alog)[k * 2 + 1];
      f32x4 ra, rb;
#pragma unroll
      for (int e = 0; e < 4; e++) { ra[e] = -__expf(a[e]); rb[e] = -__expf(b[e]); }
      ((f32x4*)na)[k * 2] = ra;
      ((f32x4*)na)[k * 2 + 1] = rb;
      continue;
    }
    k -= V_NA;
    if (k < V_DTA) {
      ((ushort8v*)dtA)[k] = (ushort8v){0,0,0,0,0,0,0,0};
      continue;
    }
    k -= V_DTA;
    {
      int e = k % (2 * DM);
      int b = (k / (2 * DM)) % BATCH;
      int l = k / (BATCH * 2 * DM);
      const float* c = cond + b * 128;
      const float* wp = adaw + ((size_t)l * (2 * DM) + e) * 128;
      float s = adab[l * (2 * DM) + e];
      for (int kk = 0; kk < 128; kk++) s = fmaf(c[kk], wp[kk], s);
      ss[k] = s;
    }
  }
}

// ---------------------------------------------------------------------------
// 128x128-tile bf16 GEMM -> bf16 out. 3-stage counted-vmcnt pipeline.
// ---------------------------------------------------------------------------
__global__ __launch_bounds__(256) void bt128b_k(
    const unsigned short* __restrict__ A, int lda,
    const unsigned short* __restrict__ W, int ldw,
    unsigned short* __restrict__ C, int ldc,
    int K) {
  __shared__ __align__(16) unsigned short As[3][128 * 32];
  __shared__ __align__(16) unsigned short Ws[3][128 * 32];
  const int tid = threadIdx.x;
  const int bm = blockIdx.y * 128;
  const int bn = blockIdx.x * 128;
  const int lane = tid & 63;
  const int wv = tid >> 6;
  const int wm = (wv >> 1) * 64;
  const int wn = (wv & 1) * 64;
  const int fr = lane & 15;
  const int fs = lane >> 4;

  const int r0 = tid >> 2;
  const int s0 = (tid & 3) ^ (r0 & 3);

  const unsigned short* gA0 = A + (size_t)(bm + r0) * lda + s0 * 8;
  const unsigned short* gA1 = A + (size_t)(bm + r0 + 64) * lda + s0 * 8;
  const unsigned short* gW0 = W + (size_t)(bn + r0) * ldw + s0 * 8;
  const unsigned short* gW1 = W + (size_t)(bn + r0 + 64) * ldw + s0 * 8;

  f32x4 acc[4][4];
#pragma unroll
  for (int i = 0; i < 4; i++)
#pragma unroll
    for (int j = 0; j < 4; j++) acc[i][j] = (f32x4){0.f, 0.f, 0.f, 0.f};

  const int nk = K >> 5;
  gl_lds16(gA0, &As[0][0] + tid * 8);
  gl_lds16(gA1, &As[0][2048] + tid * 8);
  gl_lds16(gW0, &Ws[0][0] + tid * 8);
  gl_lds16(gW1, &Ws[0][2048] + tid * 8);
  if (nk > 1) {
    gl_lds16(gA0 + 32, &As[1][0] + tid * 8);
    gl_lds16(gA1 + 32, &As[1][2048] + tid * 8);
    gl_lds16(gW0 + 32, &Ws[1][0] + tid * 8);
    gl_lds16(gW1 + 32, &Ws[1][2048] + tid * 8);
  }

  for (int kk = 0; kk < nk; kk++) {
    const int b = kk % 3;
    if (kk + 2 < nk) {
      const int k0 = (kk + 2) * 32;
      const int nb = (kk + 2) % 3;
      gl_lds16(gA0 + k0, &As[nb][0] + tid * 8);
      gl_lds16(gA1 + k0, &As[nb][2048] + tid * 8);
      gl_lds16(gW0 + k0, &Ws[nb][0] + tid * 8);
      gl_lds16(gW1 + k0, &Ws[nb][2048] + tid * 8);
    }
    const int ahead = (nk - 1 - kk >= 2) ? 2 : (nk - 1 - kk);
    if (ahead == 2)      asm volatile("s_waitcnt vmcnt(8)" : : : "memory");
    else if (ahead == 1) asm volatile("s_waitcnt vmcnt(4)" : : : "memory");
    else                 asm volatile("s_waitcnt vmcnt(0)" : : : "memory");
    __builtin_amdgcn_s_barrier();
    __builtin_amdgcn_sched_barrier(0);

    short8 af[4], bf[4];
#pragma unroll
    for (int i = 0; i < 4; i++) {
      int rowa = wm + i * 16 + fr;
      af[i] = *(const short8*)&As[b][rowa * 32 + ((fs ^ (rowa & 3)) * 8)];
      int rowb = wn + i * 16 + fr;
      bf[i] = *(const short8*)&Ws[b][rowb * 32 + ((fs ^ (rowb & 3)) * 8)];
    }
#pragma unroll
    for (int i = 0; i < 4; i++)
#pragma unroll
      for (int j = 0; j < 4; j++)
        acc[i][j] = __builtin_amdgcn_mfma_f32_16x16x32_bf16(af[i], bf[j], acc[i][j], 0, 0, 0);

    __builtin_amdgcn_s_barrier();
  }

#pragma unroll
  for (int i = 0; i < 4; i++) {
#pragma unroll
    for (int j = 0; j < 4; j++) {
#pragma unroll
      for (int r = 0; r < 4; r++) {
        int row = bm + wm + i * 16 + fs * 4 + r;
        int col = bn + wn + j * 16 + fr;
        C[(size_t)row * ldc + col] = f2bf(acc[i][j][r]);
      }
    }
  }
}

// ---------------------------------------------------------------------------
// 64x64-tile bf16 GEMM, 3-stage pipeline.
// EPI 1: softplus(v+bias)->bf16. EPI 3: fp32 partial at [z*NTOK+row] (split-K).
// ---------------------------------------------------------------------------
template<int EPI>
__global__ __launch_bounds__(256) void bt64_k(
    const unsigned short* __restrict__ A, int lda,
    const unsigned short* __restrict__ W, int ldw,
    void* __restrict__ Cv, int ldc,
    int K,
    const float* __restrict__ bias) {
  __shared__ __align__(16) unsigned short As[3][64 * 32];
  __shared__ __align__(16) unsigned short Ws[3][64 * 32];
  const int tid = threadIdx.x;
  const int bm = blockIdx.y * 64;
  const int bn = blockIdx.x * 64;
  const int kz = (EPI == 3) ? blockIdx.z : 0;
  const int lane = tid & 63;
  const int wv = tid >> 6;
  const int wm = (wv >> 1) * 32;
  const int wn = (wv & 1) * 32;
  const int fr = lane & 15;
  const int fs = lane >> 4;

  const int r0 = tid >> 2;
  const int s0 = (tid & 3) ^ (r0 & 3);

  const unsigned short* gA = A + (size_t)(bm + r0) * lda + kz * K + s0 * 8;
  const unsigned short* gW = W + (size_t)(bn + r0) * ldw + kz * K + s0 * 8;

  f32x4 acc[2][2];
#pragma unroll
  for (int i = 0; i < 2; i++)
#pragma unroll
    for (int j = 0; j < 2; j++) acc[i][j] = (f32x4){0.f, 0.f, 0.f, 0.f};

  const int nk = K >> 5;
  gl_lds16(gA, &As[0][0] + tid * 8);
  gl_lds16(gW, &Ws[0][0] + tid * 8);
  if (nk > 1) {
    gl_lds16(gA + 32, &As[1][0] + tid * 8);
    gl_lds16(gW + 32, &Ws[1][0] + tid * 8);
  }

  for (int kk = 0; kk < nk; kk++) {
    const int b = kk % 3;
    if (kk + 2 < nk) {
      const int k0 = (kk + 2) * 32;
      const int nb = (kk + 2) % 3;
      gl_lds16(gA + k0, &As[nb][0] + tid * 8);
      gl_lds16(gW + k0, &Ws[nb][0] + tid * 8);
    }
    const int ahead = (nk - 1 - kk >= 2) ? 2 : (nk - 1 - kk);
    if (ahead == 2)      asm volatile("s_waitcnt vmcnt(4)" : : : "memory");
    else if (ahead == 1) asm volatile("s_waitcnt vmcnt(2)" : : : "memory");
    else                 asm volatile("s_waitcnt vmcnt(0)" : : : "memory");
    __builtin_amdgcn_s_barrier();
    __builtin_amdgcn_sched_barrier(0);

    short8 af[2], bf[2];
#pragma unroll
    for (int i = 0; i < 2; i++) {
      int rowa = wm + i * 16 + fr;
      af[i] = *(const short8*)&As[b][rowa * 32 + ((fs ^ (rowa & 3)) * 8)];
      int rowb = wn + i * 16 + fr;
      bf[i] = *(const short8*)&Ws[b][rowb * 32 + ((fs ^ (rowb & 3)) * 8)];
    }
#pragma unroll
    for (int i = 0; i < 2; i++)
#pragma unroll
      for (int j = 0; j < 2; j++)
        acc[i][j] = __builtin_amdgcn_mfma_f32_16x16x32_bf16(af[i], bf[j], acc[i][j], 0, 0, 0);

    __builtin_amdgcn_s_barrier();
  }

#pragma unroll
  for (int i = 0; i < 2; i++) {
#pragma unroll
    for (int j = 0; j < 2; j++) {
#pragma unroll
      for (int r = 0; r < 4; r++) {
        int row = bm + wm + i * 16 + fs * 4 + r;
        int col = bn + wn + j * 16 + fr;
        float v = acc[i][j][r];
        if (EPI == 1) {
          float xv = v + bias[col];
          float sp = (xv > 20.f) ? xv : log1pf(__expf(xv));
          ((unsigned short*)Cv)[(size_t)row * ldc + col] = f2bf(sp);
        }
        if (EPI == 3) {
          ((float*)Cv)[((size_t)kz * NTOK + row) * ldc + col] = v;
        }
      }
    }
  }
}

// ---------------------------------------------------------------------------
// x_proj split-K, bf16 in, bf16 partials out
// ---------------------------------------------------------------------------
__global__ __launch_bounds__(256) void xp_k(
    const unsigned short* __restrict__ A,
    const unsigned short* __restrict__ W,
    unsigned short* __restrict__ part) {
  __shared__ __align__(16) unsigned short As[64][40];
  __shared__ __align__(16) unsigned short Ws[80][40];
  const int tid = threadIdx.x;
  const int ks = blockIdx.x;
  const int bm = blockIdx.y * 64;
  const int lane = tid & 63;
  const int wv = tid >> 6;
  const int fr = lane & 15;
  const int fs = lane >> 4;
  const int fk = fs * 8;

  const int ar = tid >> 2;
  const int ac = (tid & 3) * 8;
  const int k0base = ks * XKC;

  const unsigned short* gA  = A + (size_t)(bm + ar) * DI + k0base + ac;
  const unsigned short* gW0 = W + (size_t)ar * DI + k0base + ac;
  const unsigned short* gW1 = W + (size_t)(64 + ar) * DI + k0base + ac;

  f32x4 acc[5];
#pragma unroll
  for (int n = 0; n < 5; n++) acc[n] = (f32x4){0.f, 0.f, 0.f, 0.f};

  short8 aA, w0A, w1A;
  aA = *(const short8*)(gA);
  w0A = *(const short8*)(gW0);
  if (tid < 64) w1A = *(const short8*)(gW1);

  const int nk = XKC / 32;
  for (int kk = 0; kk < nk; kk++) {
    __syncthreads();
    *(short8*)&As[ar][ac] = aA;
    *(short8*)&Ws[ar][ac] = w0A;
    if (tid < 64) *(short8*)&Ws[64 + ar][ac] = w1A;
    __syncthreads();

    if (kk + 1 < nk) {
      const int k0 = (kk + 1) * 32;
      aA = *(const short8*)(gA + k0);
      w0A = *(const short8*)(gW0 + k0);
      if (tid < 64) w1A = *(const short8*)(gW1 + k0);
    }

    short8 af = *(const short8*)&As[wv * 16 + fr][fk];
#pragma unroll
    for (int n = 0; n < 5; n++) {
      short8 bf = *(const short8*)&Ws[n * 16 + fr][fk];
      acc[n] = __builtin_amdgcn_mfma_f32_16x16x32_bf16(af, bf, acc[n], 0, 0, 0);
    }
  }

#pragma unroll
  for (int n = 0; n < 5; n++) {
#pragma unroll
    for (int r = 0; r < 4; r++) {
      int row = bm + wv * 16 + fs * 4 + r;
      part[((size_t)ks * NTOK + row) * DBC + n * 16 + fr] = f2bf(acc[n][r]);
    }
  }
}

// sum XKS bf16 partials -> dtA bf16 (cols 0..47) / bc bf16 (cols 48..79 -> 0..31)
__global__ __launch_bounds__(256) void xp_reduce_k(const unsigned short* __restrict__ part,
                                                   unsigned short* __restrict__ dtA,
                                                   unsigned short* __restrict__ bc) {
  int i = blockIdx.x * 256 + threadIdx.x;
  const ushort4v* p4 = (const ushort4v*)part;
  const int stride4 = NTOK * DBC / 4;
  float s0 = 0.f, s1 = 0.f, s2 = 0.f, s3 = 0.f;
#pragma unroll
  for (int ks = 0; ks < XKS; ks++) {
    ushort4v v = p4[(size_t)ks * stride4 + i];
    s0 += bf2f(v[0]); s1 += bf2f(v[1]); s2 += bf2f(v[2]); s3 += bf2f(v[3]);
  }
  ushort4v o;
  o[0] = f2bf(s0); o[1] = f2bf(s1); o[2] = f2bf(s2); o[3] = f2bf(s3);
  int c4 = (i * 4) % DBC;
  int m = (i * 4) / DBC;
  if (c4 < NRANK) {
    *(ushort4v*)&dtA[(size_t)m * 64 + c4] = o;
  } else {
    *(ushort4v*)&bc[(size_t)m * 32 + (c4 - NRANK)] = o;
  }
}

// depthwise causal conv(4) + bias + silu, register-carry, ushort2 vectorized
__global__ __launch_bounds__(256) void conv_silu_k(const unsigned short* __restrict__ xz,
                                                   const float* __restrict__ cw,
                                                   const float* __restrict__ cb,
                                                   unsigned short* __restrict__ xcb) {
  const int d0 = (blockIdx.x * 256 + threadIdx.x) * 2;
  const int l0 = blockIdx.y * 16;
  const int b = blockIdx.z;
  const size_t mbase = (size_t)b * SEQ;
  const float wa0 = cw[d0 * 4 + 0], wa1 = cw[d0 * 4 + 1];
  const float wa2 = cw[d0 * 4 + 2], wa3 = cw[d0 * 4 + 3];
  const float wb0 = cw[d0 * 4 + 4], wb1 = cw[d0 * 4 + 5];
  const float wb2 = cw[d0 * 4 + 6], wb3 = cw[d0 * 4 + 7];
  const float ba = cb[d0], bb = cb[d0 + 1];

  float a3 = 0.f, a2 = 0.f, a1 = 0.f, b3 = 0.f, b2 = 0.f, b1 = 0.f;
  if (l0 >= 3) { ushort2 u = *(const ushort2*)&xz[(mbase + l0 - 3) * (2 * DI) + d0]; a3 = bf2f(u.x); b3 = bf2f(u.y); }
  if (l0 >= 2) { ushort2 u = *(const ushort2*)&xz[(mbase + l0 - 2) * (2 * DI) + d0]; a2 = bf2f(u.x); b2 = bf2f(u.y); }
  if (l0 >= 1) { ushort2 u = *(const ushort2*)&xz[(mbase + l0 - 1) * (2 * DI) + d0]; a1 = bf2f(u.x); b1 = bf2f(u.y); }
#pragma unroll
  for (int t = 0; t < 16; t++) {
    const int l = l0 + t;
    ushort2 u = *(const ushort2*)&xz[(mbase + l) * (2 * DI) + d0];
    float ca = bf2f(u.x), cbv = bf2f(u.y);
    float sa = ba + wa0 * a3 + wa1 * a2 + wa2 * a1 + wa3 * ca;
    float sb = bb + wb0 * b3 + wb1 * b2 + wb2 * b1 + wb3 * cbv;
    float ra = sa / (1.f + __expf(-sa));
    float rb = sb / (1.f + __expf(-sb));
    ushort2 o; o.x = f2bf(ra); o.y = f2bf(rb);
    *(ushort2*)&xcb[(mbase + l) * DI + d0] = o;
    a3 = a2; a2 = a1; a1 = ca;
    b3 = b2; b2 = b1; b1 = cbv;
  }
}

// ---------------------------------------------------------------------------
// scan pass 1: bf16 inputs; outputs ch_pk (cumA|hloc bf16x2), yc_pk (yloc|cumdt)
// ---------------------------------------------------------------------------
__global__ __launch_bounds__(256) void scan1_k(const unsigned short* __restrict__ dt,
                                               const unsigned short* __restrict__ xc,
                                               const unsigned short* __restrict__ bc,
                                               const float* __restrict__ negA_l,
                                               unsigned int* __restrict__ ch_pk,
                                               unsigned int* __restrict__ yc_pk) {
  __shared__ float Bs[CHLEN][DS];
  __shared__ float Cs[CHLEN][DS];
  const int tid = threadIdx.x;
  const int j = blockIdx.x;
  const int cg = blockIdx.y;
  const int b = cg / 6;
  const int d = (cg % 6) * 256 + tid;
  const int c = b * DI + d;
  const int m0 = b * SEQ + j * CHLEN;

  for (int e = tid; e < CHLEN * 32; e += 256) {
    int row = e >> 5, col = e & 31;
    float v = bf2f(bc[(size_t)(m0 + row) * 32 + col]);
    if (col < DS) Bs[row][col] = v; else Cs[row][col - DS] = v;
  }

  float Av[DS];
  const float* na = negA_l + (size_t)d * DS;
#pragma unroll
  for (int s = 0; s < DS; s++) Av[s] = na[s];
  const float Av0 = Av[0];
  bool fast = true;
#pragma unroll
  for (int s = 0; s < DS; s++)
    fast = fast && (fabsf(Av[s] - (s + 1) * Av0) <= 1e-4f * (s + 1));

  float dts[CHLEN], xcs[CHLEN];
#pragma unroll
  for (int t = 0; t < CHLEN; t++) {
    dts[t] = bf2f(dt[(size_t)(m0 + t) * DI + d]);
    xcs[t] = bf2f(xc[(size_t)(m0 + t) * DI + d]);
  }
  __syncthreads();

  float h[DS];
#pragma unroll
  for (int s = 0; s < DS; s++) h[s] = 0.f;
  float cd = 0.f;

  for (int t = 0; t < CHLEN; t++) {
    float dtv = dts[t];
    cd += dtv;
    float dtx = dtv * xcs[t];
    float ysum = 0.f;
    if (fast) {
      float e1 = __expf(dtv * Av0);
      float dA = e1;
      h[0] = fmaf(dA, h[0], dtx * Bs[t][0]);
      ysum = fmaf(h[0], Cs[t][0], ysum);
#pragma unroll
      for (int s = 1; s < DS; s++) {
        dA *= e1;
        h[s] = fmaf(dA, h[s], dtx * Bs[t][s]);
        ysum = fmaf(h[s], Cs[t][s], ysum);
      }
    } else {
#pragma unroll
      for (int s = 0; s < DS; s++) {
        float dA = __expf(dtv * Av[s]);
        h[s] = fmaf(dA, h[s], dtx * Bs[t][s]);
        ysum = fmaf(h[s], Cs[t][s], ysum);
      }
    }
    yc_pk[(size_t)(m0 + t) * DI + d] =
        (unsigned int)f2bf(ysum) | ((unsigned int)f2bf(cd) << 16);
  }

  size_t base = ((size_t)j * (BATCH * DI) + c) * DS;
#pragma unroll
  for (int s = 0; s < DS; s++) {
    unsigned int pk = (unsigned int)f2bf(__expf(cd * Av[s]))
                    | ((unsigned int)f2bf(h[s]) << 16);
    ch_pk[base + s] = pk;
  }
}

// pass 2: sequential chunk combine, 8-wide load batching for latency overlap
__global__ __launch_bounds__(256) void scan2_k(const unsigned int* __restrict__ ch_pk,
                                               unsigned short* __restrict__ hin,
                                               float* __restrict__ states_out) {
  int idx = blockIdx.x * 256 + threadIdx.x;
  const int stride = BATCH * DI * DS;
  float h = 0.f;
  for (int g = 0; g < NCHUNK / 8; g++) {
    unsigned int pks[8];
#pragma unroll
    for (int u = 0; u < 8; u++)
      pks[u] = ch_pk[(size_t)(g * 8 + u) * stride + idx];
#pragma unroll
    for (int u = 0; u < 8; u++) {
      hin[(size_t)(g * 8 + u) * stride + idx] = f2bf(h);
      h = fmaf(bf2f((unsigned short)(pks[u] & 0xFFFF)), h,
               bf2f((unsigned short)(pks[u] >> 16)));
    }
  }
  states_out[idx] = h;
}

// pass 3: parallel fixup
__global__ __launch_bounds__(256) void scanfix_k(const unsigned int* __restrict__ yc_pk,
                                                 const unsigned short* __restrict__ xc,
                                                 const unsigned short* __restrict__ xz,
                                                 const unsigned short* __restrict__ bc,
                                                 const float* __restrict__ negA_l,
                                                 const float* __restrict__ Dsk,
                                                 const unsigned short* __restrict__ hin,
                                                 unsigned short* __restrict__ y) {
  int idx = blockIdx.x * 256 + threadIdx.x;
  int d = idx % DI;
  int m = idx / DI;
  int b = m / SEQ;
  int j = (m % SEQ) / CHLEN;
  unsigned int pk = yc_pk[idx];
  float yv = bf2f((unsigned short)(pk & 0xFFFF));
  float cd = bf2f((unsigned short)(pk >> 16));
  const f32x4* na4 = (const f32x4*)(negA_l + (size_t)d * DS);
  const ushort4v* cp4 = (const ushort4v*)(bc + (size_t)m * 32 + DS);
  const ushort4v* h4 = (const ushort4v*)(hin + ((size_t)j * (BATCH * DI) + (size_t)b * DI + d) * DS);
  float corr = 0.f;
#pragma unroll
  for (int q = 0; q < 4; q++) {
    f32x4 na = na4[q];
    ushort4v cp = cp4[q];
    ushort4v hh = h4[q];
#pragma unroll
    for (int e = 0; e < 4; e++)
      corr = fmaf(__expf(cd * na[e]) * bf2f(hh[e]), bf2f(cp[e]), corr);
  }
  yv += corr;
  float xv = bf2f(xc[idx]);
  float zv = bf2f(xz[(size_t)m * (2 * DI) + DI + d]);
  float sig = 1.f / (1.f + __expf(-zv));
  y[idx] = f2bf((yv + Dsk[d] * xv) * (zv * sig));
}

// LN. ADA=true: input = part[0]+part[1]+resid (out_proj split-K fold), then
// LN(w,b) -> LN_noaffine -> adaln modulate, writes h fp32 + bf16.
// ADA=false: input = in (fp32), plain LN(w,b) -> out.
template<bool ADA>
__global__ __launch_bounds__(256) void ln_k(const float* __restrict__ in,
                                            const float* __restrict__ resid,
                                            const float* __restrict__ w,
                                            const float* __restrict__ bb,
                                            const float* __restrict__ ss,
                                            float* __restrict__ out,
                                            unsigned short* __restrict__ outb) {
  __shared__ float red[8];
  const int row = blockIdx.x;
  const int bt = row / SEQ;
  const int tid = threadIdx.x;
  float v[3];
#pragma unroll
  for (int i = 0; i < 3; i++) {
    int c = tid + i * 256;
    if (ADA) {
      v[i] = in[(size_t)row * DM + c] + in[(size_t)(NTOK + row) * DM + c]
           + resid[(size_t)row * DM + c];
    } else {
      v[i] = in[(size_t)row * DM + c];
    }
  }
  float s1 = v[0] + v[1] + v[2];
  float s2 = v[0]*v[0] + v[1]*v[1] + v[2]*v[2];
#pragma unroll
  for (int o = 32; o > 0; o >>= 1) { s1 += __shfl_down(s1, o); s2 += __shfl_down(s2, o); }
  int wv = tid >> 6, ln = tid & 63;
  if (ln == 0) { red[wv*2] = s1; red[wv*2+1] = s2; }
  __syncthreads();
  s1 = red[0] + red[2] + red[4] + red[6];
  s2 = red[1] + red[3] + red[5] + red[7];
  float mu = s1 * (1.f / DM);
  float var = s2 * (1.f / DM) - mu * mu;
  float rs = rsqrtf(var + 1e-5f);
  float t[3];
#pragma unroll
  for (int i = 0; i < 3; i++) {
    int c = tid + i * 256;
    t[i] = (v[i] - mu) * rs * w[c] + bb[c];
  }
  if (!ADA) {
#pragma unroll
    for (int i = 0; i < 3; i++) out[(size_t)row * DM + tid + i * 256] = t[i];
    return;
  }
  __syncthreads();
  s1 = t[0] + t[1] + t[2];
  s2 = t[0]*t[0] + t[1]*t[1] + t[2]*t[2];
#pragma unroll
  for (int o = 32; o > 0; o >>= 1) { s1 += __shfl_down(s1, o); s2 += __shfl_down(s2, o); }
  if (ln == 0) { red[wv*2] = s1; red[wv*2+1] = s2; }
  __syncthreads();
  s1 = red[0] + red[2] + red[4] + red[6];
  s2 = red[1] + red[3] + red[5] + red[7];
  float mu2 = s1 * (1.f / DM);
  float var2 = s2 * (1.f / DM) - mu2 * mu2;
  float rs2 = rsqrtf(var2 + 1e-5f);
#pragma unroll
  for (int i = 0; i < 3; i++) {
    int c = tid + i * 256;
    float sc = ss[bt * (2 * DM) + c];
    float sh = ss[bt * (2 * DM) + DM + c];
    float r = (t[i] - mu2) * rs2 * (1.f + sc) + sh;
    out[(size_t)row * DM + c] = r;
    outb[(size_t)row * DM + c] = f2bf(r);
  }
}

extern "C" void kernel_launch(void* const* d_in, const int* in_sizes, int n_in,
                              void* d_out, int out_size, void* d_ws, size_t ws_size,
                              hipStream_t stream) {
  const float* x      = (const float*)d_in[0];
  const float* cond   = (const float*)d_in[1];
  const float* in_w   = (const float*)d_in[2];
  const float* conv_w = (const float*)d_in[3];
  const float* conv_b = (const float*)d_in[4];
  const float* xp_w   = (const float*)d_in[5];
  const float* dtp_w  = (const float*)d_in[6];
  const float* dtp_b  = (const float*)d_in[7];
  const float* A_log  = (const float*)d_in[8];
  const float* Dsk    = (const float*)d_in[9];
  const float* out_w  = (const float*)d_in[10];
  const float* norm_w = (const float*)d_in[11];
  const float* norm_b = (const float*)d_in[12];
  const float* ada_w  = (const float*)d_in[13];
  const float* ada_b  = (const float*)d_in[14];
  const float* fn_w   = (const float*)d_in[15];
  const float* fn_b   = (const float*)d_in[16];

  float* out_h = (float*)d_out;
  float* out_states = out_h + (size_t)NTOK * DM;

  float* p = (float*)d_ws;
  float* h_cur = p; p += (size_t)NTOK * DM;
  float* part2 = p; p += (size_t)2 * NTOK * DM;   // out_proj split-K partials
  float* ss    = p; p += (size_t)NL * BATCH * 2 * DM;
  float* negA  = p; p += (size_t)NL * DI * DS;
  unsigned int* ch_pk = (unsigned int*)p; p += (size_t)NCHUNK * BATCH * DI * DS;
  unsigned int* yc_pk = (unsigned int*)p; p += (size_t)NTOK * DI;
  unsigned short* q = (unsigned short*)p;
  unsigned short* hin      = q; q += (size_t)NCHUNK * BATCH * DI * DS;
  unsigned short* in_w_bf  = q; q += (size_t)NL * 2 * DI * DM;
  unsigned short* out_w_bf = q; q += (size_t)NL * DM * DI;
  unsigned short* xp_w_bf  = q; q += (size_t)NL * DBC * DI;
  unsigned short* dtw_bf   = q; q += (size_t)NL * DI * 64;
  unsigned short* h_bf     = q; q += (size_t)NTOK * DM;
  unsigned short* xz_bf    = q; q += (size_t)NTOK * 2 * DI;
  unsigned short* xc_bf    = q; q += (size_t)NTOK * DI;
  unsigned short* dtb_bf   = q; q += (size_t)NTOK * DI;
  unsigned short* yb_bf    = q; q += (size_t)NTOK * DI;
  unsigned short* part_bf  = q; q += (size_t)XKS * NTOK * DBC;
  unsigned short* dtA_bf   = q; q += (size_t)NTOK * 64;
  unsigned short* bc_bf    = q; q += (size_t)NTOK * 32;

  cvt_k<<<2048, 256, 0, stream>>>(x, in_w, out_w, xp_w, dtp_w, A_log,
                                  cond, ada_w, ada_b,
                                  h_bf, in_w_bf, out_w_bf, xp_w_bf, dtw_bf,
                                  negA, dtA_bf, ss);

  for (int l = 0; l < NL; l++) {
    // in_proj -> xz (bf16)
    bt128b_k<<<dim3(24, 16), 256, 0, stream>>>(
        h_bf, DM, in_w_bf + (size_t)l * 2 * DI * DM, DM, xz_bf, 2 * DI, DM);
    // conv + silu -> xc (bf16)
    conv_silu_k<<<dim3(DI / 512, SEQ / 16, BATCH), 256, 0, stream>>>(
        xz_bf, conv_w + (size_t)l * DI * 4, conv_b + (size_t)l * DI, xc_bf);
    // x_proj split-K (bf16 partials)
    xp_k<<<dim3(XKS, NTOK / 64), 256, 0, stream>>>(
        xc_bf, xp_w_bf + (size_t)l * DBC * DI, part_bf);
    xp_reduce_k<<<NTOK * DBC / 4 / 256, 256, 0, stream>>>(part_bf, dtA_bf, bc_bf);
    // dt_proj + softplus -> dtb (bf16)
    bt64_k<1><<<dim3(DI / 64, NTOK / 64), 256, 0, stream>>>(
        dtA_bf, 64, dtw_bf + (size_t)l * DI * 64, 64, dtb_bf, DI,
        64, dtp_b + (size_t)l * DI);
    // scan trio
    scan1_k<<<dim3(NCHUNK, 12), 256, 0, stream>>>(
        dtb_bf, xc_bf, bc_bf, negA + (size_t)l * DI * DS, ch_pk, yc_pk);
    scan2_k<<<192, 256, 0, stream>>>(
        ch_pk, hin, out_states + (size_t)l * BATCH * DI * DS);
    scanfix_k<<<NTOK * DI / 256, 256, 0, stream>>>(
        yc_pk, xc_bf, xz_bf, bc_bf, negA + (size_t)l * DI * DS,
        Dsk + (size_t)l * DI, hin, yb_bf);
    // out_proj split-K=2 -> fp32 partials (resid folded into ln)
    bt64_k<3><<<dim3(DM / 64, NTOK / 64, 2), 256, 0, stream>>>(
        yb_bf, DI, out_w_bf + (size_t)l * DM * DI, DI, part2, DM,
        DI / 2, nullptr);
    // LN(part0+part1+resid) + adaln modulate
    ln_k<true><<<NTOK, 256, 0, stream>>>(
        part2, (l == 0) ? x : h_cur,
        norm_w + (size_t)l * DM, norm_b + (size_t)l * DM,
        ss + (size_t)l * BATCH * 2 * DM, h_cur, h_bf);
  }
  ln_k<false><<<NTOK, 256, 0, stream>>>(h_cur, nullptr, fn_w, fn_b, nullptr,
                                        out_h, nullptr);
}